// Round 13
// baseline (114.448 us; speedup 1.0000x reference)
//
#include <hip/hip_runtime.h>
#include <math.h>

#define TAUF  1.0e-4f
#define LNEPS 1.0e-5f

typedef __bf16 bf16x8 __attribute__((ext_vector_type(8)));
typedef float  f32x4  __attribute__((ext_vector_type(4)));

union U4 { uint4 u4; unsigned short us[8]; bf16x8 bv; };

static __device__ __forceinline__ unsigned short f2bf(float f) {
    union { float f; unsigned u; } v; v.f = f;
    unsigned r = v.u + 0x7fffu + ((v.u >> 16) & 1u);
    return (unsigned short)(r >> 16);
}
static __device__ __forceinline__ float bf2f(unsigned short h) {
    union { unsigned u; float f; } v; v.u = ((unsigned)h) << 16;
    return v.f;
}

// ---------------- workspace layout (float offsets, all 16B-aligned) ----------------
static const unsigned CE_OFF   = 0u;         // 768
static const unsigned B0_OFF   = 768u;       // 256
static const unsigned C1_OFF   = 1024u;      // 256
static const unsigned R2_OFF   = 1280u;      // 16
static const unsigned UF_OFF   = 1296u;      // 18*64 uint4 = 4608 f
static const unsigned B1F_OFF  = 5904u;      // 4*64 uint4  = 1024 f
static const unsigned GF_OFF   = 6928u;      // 18*64 uint4 = 4608 f
static const unsigned QT_OFF   = 11536u;     // 393216 bf16 = 196608 f
static const unsigned W1T_OFF  = 208144u;    // 262144 bf16 = 131072 f
static const unsigned W2T_OFF  = 339216u;    // 262144 bf16 = 131072 f
static const unsigned WS_FLOATS = 470288u;   // ~1.9 MB

// ================= prep: ALL x-independent prep in ONE launch (unchanged from R12) =================
__launch_bounds__(256, 2)
__global__ void prep_k(const float* __restrict__ wv0_w, const float* __restrict__ wein_w,
                       const float* __restrict__ out_w,
                       const float* __restrict__ ffn1_w, const float* __restrict__ ffn2_w,
                       const float* __restrict__ wv0_b, const float* __restrict__ wein_b,
                       const float* __restrict__ out_b,
                       const float* __restrict__ B1g, const float* __restrict__ absB1,
                       const float* __restrict__ B2g,
                       unsigned short* __restrict__ Qt,
                       unsigned short* __restrict__ w1t, unsigned short* __restrict__ w2t,
                       float* __restrict__ ce, float* __restrict__ bias0,
                       float* __restrict__ C1, float* __restrict__ r2,
                       uint4* __restrict__ ufrag, uint4* __restrict__ b1frag,
                       uint4* __restrict__ gfrag)
{
    __shared__ float sPool[12800];             // 51.2 KB, aliased per branch
    int b = blockIdx.x, tid = threadIdx.x;
    if (b < 96) {
        float* sTf = sPool;                                     // [64][68] f32
        unsigned short* sBb = (unsigned short*)(sPool + 4352);  // [64][264] bf16
        int by = b >> 2, bx = b & 3;
        int row0 = by * 64, col0 = bx * 64;
        int z = row0 >> 8, o0 = row0 & 255;
        int s = (z < 3) ? z : z - 3;
        const float* Wsel = (z < 3) ? wv0_w : wein_w;
        int lane = tid & 63, w = tid >> 6;
        int rr = lane & 15, kq = lane >> 4;

        #pragma unroll
        for (int i = 0; i < 16; ++i) {
            int idx = i*256 + tid;
            int row = idx >> 6, c4 = idx & 63;
            float4 v = *(const float4*)(Wsel + (size_t)(col0 + row)*768 + s*256 + c4*4);
            ushort4 pk;
            pk.x = f2bf(v.x); pk.y = f2bf(v.y); pk.z = f2bf(v.z); pk.w = f2bf(v.w);
            *(ushort4*)&sBb[row*264 + c4*4] = pk;
        }
        __syncthreads();

        f32x4 acc[4];
        #pragma unroll
        for (int cg = 0; cg < 4; ++cg) acc[cg] = 0.f;
        for (int st = 0; st < 4; ++st) {
            #pragma unroll
            for (int i = 0; i < 4; ++i) {
                int idx = i*256 + tid;
                int dd = idx >> 4, q = idx & 15;
                float4 v = *(const float4*)(out_w + (size_t)(z*256 + st*64 + dd)*256 + o0 + q*4);
                *(float4*)&sTf[dd*68 + q*4] = v;
            }
            __syncthreads();
            #pragma unroll
            for (int ks2 = 0; ks2 < 2; ++ks2) {
                int ks = st*2 + ks2;
                U4 av;
                #pragma unroll
                for (int j = 0; j < 8; ++j)
                    av.us[j] = f2bf(sTf[(ks2*32 + kq*8 + j)*68 + w*16 + rr]);
                #pragma unroll
                for (int cg = 0; cg < 4; ++cg) {
                    bf16x8 bv = *(const bf16x8*)&sBb[(cg*16 + rr)*264 + ks*32 + kq*8];
                    acc[cg] = __builtin_amdgcn_mfma_f32_16x16x32_bf16(av.bv, bv, acc[cg], 0, 0, 0);
                }
            }
            __syncthreads();
        }
        #pragma unroll
        for (int cg = 0; cg < 4; ++cg)
            #pragma unroll
            for (int e = 0; e < 4; ++e) {
                int row = row0 + w*16 + kq*4 + e;
                int col = col0 + cg*16 + rr;
                Qt[(size_t)row*256 + col] = f2bf(acc[cg][e]);
            }
    } else if (b < 352) {
        float (*tile)[33] = (float(*)[33])sPool;
        int bi = b - 96;
        int c0 = (bi & 31) * 32, r0 = (bi >> 5) * 32;
        int tx = tid & 31, ty = tid >> 5;
        #pragma unroll
        for (int i = 0; i < 4; ++i)
            tile[ty + i*8][tx] = ffn1_w[(size_t)(r0 + ty + i*8)*1024 + c0 + tx];
        __syncthreads();
        #pragma unroll
        for (int i = 0; i < 4; ++i)
            w1t[(size_t)(c0 + ty + i*8)*256 + r0 + tx] = f2bf(tile[tx][ty + i*8]);
    } else if (b < 608) {
        float (*tile)[33] = (float(*)[33])sPool;
        int bi = b - 352;
        int c0 = (bi & 7) * 32, r0 = (bi >> 3) * 32;
        int tx = tid & 31, ty = tid >> 5;
        #pragma unroll
        for (int i = 0; i < 4; ++i)
            tile[ty + i*8][tx] = ffn2_w[(size_t)(r0 + ty + i*8)*256 + c0 + tx];
        __syncthreads();
        #pragma unroll
        for (int i = 0; i < 4; ++i)
            w2t[(size_t)(c0 + ty + i*8)*1024 + r0 + tx] = f2bf(tile[tx][ty + i*8]);
    } else if (b < 612) {
        float (*sW)[257] = (float(*)[257])sPool;
        int which = b - 608;
        int o = tid;
        float acc = 0.f;
        if (which == 3) {
            for (int rc = 0; rc < 768; rc += 32) {
                #pragma unroll
                for (int i = 0; i < 32; ++i) sW[i][tid] = out_w[(size_t)(rc+i)*256 + tid];
                __syncthreads();
                #pragma unroll
                for (int i = 0; i < 32; ++i) acc += wv0_b[rc+i] * sW[i][tid];
                __syncthreads();
            }
            bias0[o] = out_b[o] + TAUF * acc;
        } else {
            int base = 768 + which*256;
            for (int rc = 0; rc < 256; rc += 32) {
                #pragma unroll
                for (int i = 0; i < 32; ++i) sW[i][tid] = out_w[(size_t)(base+rc+i)*256 + tid];
                __syncthreads();
                #pragma unroll
                for (int i = 0; i < 32; ++i) acc += wein_b[which*256 + rc+i] * sW[i][tid];
                __syncthreads();
            }
            ce[which*256 + o] = acc;
        }
    } else if (b == 612) {
        int p = tid >> 4, q = tid & 15;
        float c1 = 0.f;
        for (int e = 0; e < 120; ++e) c1 += absB1[p*120+e] * absB1[q*120+e];
        C1[tid] = c1;
        if (tid < 16) {
            float bb = 0.f;
            for (int e = 0; e < 120; ++e) bb += absB1[tid*120+e];
            r2[tid] = bb;
        }
    } else if (b < 631) {
        unsigned short (*sFrag)[8] = (unsigned short(*)[8])sPool;
        int kt = b - 613;
        #pragma unroll
        for (int it = 0; it < 2; ++it) {
            int item = it*256 + tid;
            int lane = item >> 3, j = item & 7;
            int col = lane & 15, kq = lane >> 4;
            int t = kt*32 + kq*8 + j;
            float v = 0.f;
            if (t < 560) {
                for (int e = 0; e < 120; ++e) v += absB1[col*120+e] * B2g[e*560+t];
            } else {
                int p = t - 560;
                for (int e = 0; e < 120; ++e) v += absB1[col*120+e] * B1g[p*120+e];
            }
            sFrag[lane][j] = f2bf(v);
        }
        __syncthreads();
        if (tid < 64) {
            U4 o;
            #pragma unroll
            for (int j = 0; j < 8; ++j) o.us[j] = sFrag[tid][j];
            ufrag[kt*64 + tid] = o.u4;
        }
    } else if (b < 635) {
        if (tid < 64) {
            int lane = tid, col = lane & 15, kq = lane >> 4;
            int kt = b - 631;
            U4 o;
            #pragma unroll
            for (int j = 0; j < 8; ++j) {
                int e = kt*32 + kq*8 + j;
                o.us[j] = f2bf((e < 120) ? B1g[col*120 + e] : 0.f);
            }
            b1frag[kt*64 + lane] = o.u4;
        }
    } else {
        unsigned short (*sFrag)[8] = (unsigned short(*)[8])sPool;
        int kt = b - 635;
        #pragma unroll
        for (int it = 0; it < 2; ++it) {
            int item = it*256 + tid;
            int lane = item >> 3, j = item & 7;
            int col = lane & 15, kq = lane >> 4;
            int t = kt*32 + kq*8 + j;
            float g;
            if (t < 560) {
                float u = 0.f, sgv = 0.f;
                for (int e = 0; e < 120; ++e) {
                    float bv = B2g[e*560+t];
                    u += absB1[col*120+e] * bv;
                    sgv += bv;
                }
                g = sgv * u;
            } else {
                int p = t - 560;
                float c0 = 0.f, r1v = 0.f;
                for (int e = 0; e < 120; ++e) {
                    float bv = B1g[p*120+e];
                    c0 += absB1[col*120+e] * bv;
                    r1v += bv;
                }
                g = c0 * r1v;
            }
            sFrag[lane][j] = f2bf(g);
        }
        __syncthreads();
        if (tid < 64) {
            U4 o;
            #pragma unroll
            for (int j = 0; j < 8; ++j) o.us[j] = sFrag[tid][j];
            gfrag[kt*64 + tid] = o.u4;
        }
    }
}

// ============== k_mega: R12 structure, F rebuilt wave-local (0 barriers, no sYb) ==============
__launch_bounds__(1024, 4)
__global__ void k_mega(const float* __restrict__ x, const float* __restrict__ mask,
                       const int* __restrict__ e_i, const int* __restrict__ e_j,
                       const int* __restrict__ t_ij, const int* __restrict__ t_jk,
                       const int* __restrict__ t_ik,
                       const float* __restrict__ geom_w, const float* __restrict__ geom_b,
                       const float* __restrict__ log_sc,
                       const float* __restrict__ n1_g, const float* __restrict__ n1_b,
                       const float* __restrict__ n2g, const float* __restrict__ n2b,
                       const float* __restrict__ C1, const float* __restrict__ r2,
                       const uint4* __restrict__ ufrag, const uint4* __restrict__ b1frag,
                       const uint4* __restrict__ gfrag,
                       const unsigned short* __restrict__ Qt,
                       const float* __restrict__ bias0, const float* __restrict__ ce,
                       const unsigned short* __restrict__ w1t, const float* __restrict__ f1b,
                       const unsigned short* __restrict__ w2t, const float* __restrict__ f2b,
                       float* __restrict__ outp)
{
    __shared__ float sFbuf[16][264];           // xn (phases A-B), then x2 (F-I)
    __shared__ unsigned short sNB[16*256];     // bf16 xn chunks (A-F), then x2n chunks (G-H)
    __shared__ unsigned short sH[16*1024];     // h, frag layout (FFN2 A-frags)
    __shared__ float sP[16][17];
    __shared__ float sW1e[3][128];
    __shared__ float sW2e[3][576];
    __shared__ float sMask[16];
    __shared__ float sO[6*256];
    __shared__ float sRsA[48];

    const int bb = blockIdx.x, tid = threadIdx.x;
    const int w = tid >> 6, lane = tid & 63;
    const int rr = lane & 15, kq = lane >> 4;

    // ---- A. LayerNorm 1: wave w = row w, 64 lanes x 4 elems ----
    {
        const int r = w, q = lane;
        const float* row = x + ((size_t)bb*16 + r)*256 + q*4;
        float4 va = *(const float4*)row;
        float v[4] = {va.x, va.y, va.z, va.w};
        float sum = v[0]+v[1]+v[2]+v[3];
        float ss  = v[0]*v[0]+v[1]*v[1]+v[2]*v[2]+v[3]*v[3];
        #pragma unroll
        for (int o = 32; o; o >>= 1) { sum += __shfl_xor(sum, o); ss += __shfl_xor(ss, o); }
        float mean = sum * (1.f/256.f);
        float rstd = rsqrtf(ss*(1.f/256.f) - mean*mean + LNEPS);
        ushort4 pk;
        float xv0 = (v[0]-mean)*rstd*n1_g[q*4+0] + n1_b[q*4+0];
        float xv1 = (v[1]-mean)*rstd*n1_g[q*4+1] + n1_b[q*4+1];
        float xv2 = (v[2]-mean)*rstd*n1_g[q*4+2] + n1_b[q*4+2];
        float xv3 = (v[3]-mean)*rstd*n1_g[q*4+3] + n1_b[q*4+3];
        sFbuf[r][q*4+0] = xv0; sFbuf[r][q*4+1] = xv1;
        sFbuf[r][q*4+2] = xv2; sFbuf[r][q*4+3] = xv3;
        pk.x = f2bf(xv0); pk.y = f2bf(xv1); pk.z = f2bf(xv2); pk.w = f2bf(xv3);
        int kg = q >> 1;
        int swz = (kg & 24) | ((kg & 7) ^ (r & 7));
        *(ushort4*)&sNB[r*256 + swz*8 + (q & 1)*4] = pk;
        if (tid < 16) sMask[tid] = mask[bb*16 + tid];
    }
    __syncthreads();

    // ---- B. P = xn @ geom_w + geom_b: (r, g, quarter), global geom_w ----
    {
        const int r = w, g = (lane >> 2) & 15, quarter = lane & 3;
        const int cb = quarter * 64;
        float a0 = 0.f, a1 = 0.f, a2 = 0.f, a3 = 0.f;
        #pragma unroll
        for (int c = 0; c < 64; c += 4) {
            float4 xv = *(const float4*)&sFbuf[r][cb + c];
            a0 += xv.x * geom_w[(cb+c+0)*16 + g];
            a1 += xv.y * geom_w[(cb+c+1)*16 + g];
            a2 += xv.z * geom_w[(cb+c+2)*16 + g];
            a3 += xv.w * geom_w[(cb+c+3)*16 + g];
        }
        float p = (a0+a1) + (a2+a3);
        p += __shfl_xor(p, 1);
        p += __shfl_xor(p, 2);
        if (quarter == 0) sP[r][g] = p + geom_b[g];
    }
    __syncthreads();

    // ---- C. W1: e = tid>>3, s = tid&7 ----
    {
        int e = tid >> 3, s = tid & 7;
        if (e < 120 && s < 3) {
            int i0 = e_i[e], j0 = e_j[e];
            float d2 = 0.f;
            #pragma unroll
            for (int m = 0; m < 16; ++m) { float dd = sP[i0][m] - sP[j0][m]; d2 += dd*dd; }
            float mm = sMask[i0]*sMask[j0];
            d2 *= mm*mm;
            float sc = expf(log_sc[s]);
            sW1e[s][e] = expf(-d2/(2.f*sc*sc + 1e-8f)) * mm;
        }
        if (tid < 24) sW1e[tid >> 3][120 + (tid & 7)] = 0.f;
    }
    __syncthreads();

    // ---- D. W2 + mask extension ----
    if (tid < 560) {
        int t = tid;
        int a = t_ij[t], b2 = t_jk[t], c2 = t_ik[t];
        #pragma unroll
        for (int s = 0; s < 3; ++s) sW2e[s][t] = sW1e[s][a]*sW1e[s][b2]*sW1e[s][c2];
    }
    if (tid < 48) sW2e[tid >> 4][560 + (tid & 15)] = sMask[tid & 15];
    __syncthreads();

    // ---- E. waves 0-2: edge O; wave 3: node O; wave 4: rsA via gfrag MFMA ----
    if (w < 3) {
        int s = w;
        f32x4 acc = {0.f, 0.f, 0.f, 0.f};
        __builtin_amdgcn_s_setprio(1);
        #pragma unroll 3
        for (int kt = 0; kt < 18; ++kt) {
            U4 ub; ub.u4 = ufrag[kt*64 + lane];
            const float4* w4 = (const float4*)&sW2e[s][kt*32 + kq*8];
            float4 wa = w4[0], wb = w4[1];
            U4 av;
            av.us[0] = f2bf(wa.x * bf2f(ub.us[0]));
            av.us[1] = f2bf(wa.y * bf2f(ub.us[1]));
            av.us[2] = f2bf(wa.z * bf2f(ub.us[2]));
            av.us[3] = f2bf(wa.w * bf2f(ub.us[3]));
            av.us[4] = f2bf(wb.x * bf2f(ub.us[4]));
            av.us[5] = f2bf(wb.y * bf2f(ub.us[5]));
            av.us[6] = f2bf(wb.z * bf2f(ub.us[6]));
            av.us[7] = f2bf(wb.w * bf2f(ub.us[7]));
            acc = __builtin_amdgcn_mfma_f32_16x16x32_bf16(av.bv, ub.bv, acc, 0, 0, 0);
        }
        __builtin_amdgcn_s_setprio(0);
        #pragma unroll
        for (int e = 0; e < 4; ++e) {
            int row = kq*4 + e;
            sO[(3+s)*256 + row*16 + rr] = acc[e] + TAUF*C1[row*16 + rr];
        }
    } else if (w == 3) {
        f32x4 acc3[3];
        acc3[0] = 0.f; acc3[1] = 0.f; acc3[2] = 0.f;
        __builtin_amdgcn_s_setprio(1);
        #pragma unroll
        for (int kt = 0; kt < 4; ++kt) {
            U4 ub; ub.u4 = b1frag[kt*64 + lane];
            float uf[8];
            #pragma unroll
            for (int j = 0; j < 8; ++j) uf[j] = bf2f(ub.us[j]);
            #pragma unroll
            for (int s = 0; s < 3; ++s) {
                const float4* w4 = (const float4*)&sW1e[s][kt*32 + kq*8];
                float4 wa = w4[0], wb = w4[1];
                U4 av;
                av.us[0] = f2bf(wa.x * uf[0]);
                av.us[1] = f2bf(wa.y * uf[1]);
                av.us[2] = f2bf(wa.z * uf[2]);
                av.us[3] = f2bf(wa.w * uf[3]);
                av.us[4] = f2bf(wb.x * uf[4]);
                av.us[5] = f2bf(wb.y * uf[5]);
                av.us[6] = f2bf(wb.z * uf[6]);
                av.us[7] = f2bf(wb.w * uf[7]);
                acc3[s] = __builtin_amdgcn_mfma_f32_16x16x32_bf16(av.bv, ub.bv, acc3[s], 0, 0, 0);
            }
        }
        __builtin_amdgcn_s_setprio(0);
        #pragma unroll
        for (int s = 0; s < 3; ++s)
            #pragma unroll
            for (int e = 0; e < 4; ++e) {
                int row = kq*4 + e;
                sO[s*256 + row*16 + rr] = acc3[s][e] + ((row == rr) ? TAUF : 0.f);
            }
    } else if (w == 4) {
        f32x4 acc = {0.f, 0.f, 0.f, 0.f};
        int srow = (rr < 3) ? rr : 0;
        __builtin_amdgcn_s_setprio(1);
        #pragma unroll 3
        for (int kt = 0; kt < 18; ++kt) {
            U4 gb; gb.u4 = gfrag[kt*64 + lane];
            const float4* w4 = (const float4*)&sW2e[srow][kt*32 + kq*8];
            float4 wa = w4[0], wb = w4[1];
            U4 av;
            av.us[0] = f2bf(wa.x); av.us[1] = f2bf(wa.y);
            av.us[2] = f2bf(wa.z); av.us[3] = f2bf(wa.w);
            av.us[4] = f2bf(wb.x); av.us[5] = f2bf(wb.y);
            av.us[6] = f2bf(wb.z); av.us[7] = f2bf(wb.w);
            acc = __builtin_amdgcn_mfma_f32_16x16x32_bf16(av.bv, gb.bv, acc, 0, 0, 0);
        }
        __builtin_amdgcn_s_setprio(0);
        if (kq == 0) {
            #pragma unroll
            for (int e = 0; e < 3; ++e)
                sRsA[e*16 + rr] = acc[e] + TAUF * r2[rr];
        }
    }
    __syncthreads();

    // ---- F. wave-local Y-GEMM + in-register O-contraction: NO barriers, no sYb ----
    // wave w owns cols [w*16, w*16+16); ya[e] = Y[kq*4+e][w*16+rr] (m89 C-layout)
    {
        const int col = w*16 + rr;
        float accP[16];
        #pragma unroll
        for (int k = 0; k < 16; ++k) accP[k] = 0.f;
        float xr[4];
        #pragma unroll
        for (int e = 0; e < 4; ++e)
            xr[e] = x[((size_t)bb*16 + kq*4 + e)*256 + col];
        U4 qf[8];
        #pragma unroll
        for (int kt = 0; kt < 8; ++kt)
            qf[kt].u4 = *(const uint4*)(Qt + ((size_t)(w*16 + rr))*256 + kt*32 + kq*8);
        for (int blk = 0; blk < 6; ++blk) {
            f32x4 ya = {0.f, 0.f, 0.f, 0.f};
            __builtin_amdgcn_s_setprio(1);
            #pragma unroll
            for (int kt = 0; kt < 8; ++kt) {
                int kg = kt*4 + kq;
                int swz = (kg & 24) | ((kg & 7) ^ (rr & 7));
                bf16x8 af = *(const bf16x8*)&sNB[rr*256 + swz*8];
                ya = __builtin_amdgcn_mfma_f32_16x16x32_bf16(af, qf[kt].bv, ya, 0, 0, 0);
            }
            __builtin_amdgcn_s_setprio(0);
            if (blk < 5) {
                #pragma unroll
                for (int kt = 0; kt < 8; ++kt)
                    qf[kt].u4 = *(const uint4*)(Qt + ((size_t)((blk+1)*256 + w*16 + rr))*256 + kt*32 + kq*8);
            }
            // x2 partial: accP[k] += O[k][kq*4+e] * ya[e]  (float4 broadcast LDS reads)
            #pragma unroll
            for (int k = 0; k < 16; ++k) {
                float4 ov = *(const float4*)&sO[blk*256 + k*16 + kq*4];
                accP[k] += ov.x*ya[0] + ov.y*ya[1] + ov.z*ya[2] + ov.w*ya[3];
            }
        }
        // reduce the 4 kq-group partials (lane bits 4-5)
        #pragma unroll
        for (int k = 0; k < 16; ++k) {
            accP[k] += __shfl_xor(accP[k], 16);
            accP[k] += __shfl_xor(accP[k], 32);
        }
        float b0v = bias0[col], c0v = ce[col], c1v = ce[256+col], c2v = ce[512+col];
        #pragma unroll
        for (int e = 0; e < 4; ++e) {
            int k = kq*4 + e;
            float v = accP[k] + b0v
                    + sRsA[     k] * c0v
                    + sRsA[16 + k] * c1v
                    + sRsA[32 + k] * c2v
                    + xr[e];
            sFbuf[k][col] = v;       // x2 (xn dead)
        }
    }
    __syncthreads();

    // ---- G. LN2 -> sNB (x2n bf16 chunks) ----
    {
        const int r = w, q = lane;
        float v[4];
        v[0] = sFbuf[r][q*4+0]; v[1] = sFbuf[r][q*4+1];
        v[2] = sFbuf[r][q*4+2]; v[3] = sFbuf[r][q*4+3];
        float sum = v[0]+v[1]+v[2]+v[3];
        float ss  = v[0]*v[0]+v[1]*v[1]+v[2]*v[2]+v[3]*v[3];
        #pragma unroll
        for (int o = 32; o; o >>= 1) { sum += __shfl_xor(sum, o); ss += __shfl_xor(ss, o); }
        float mean = sum * (1.f/256.f);
        float rstd = rsqrtf(ss*(1.f/256.f) - mean*mean + LNEPS);
        ushort4 pk;
        pk.x = f2bf((v[0]-mean)*rstd*n2g[q*4+0] + n2b[q*4+0]);
        pk.y = f2bf((v[1]-mean)*rstd*n2g[q*4+1] + n2b[q*4+1]);
        pk.z = f2bf((v[2]-mean)*rstd*n2g[q*4+2] + n2b[q*4+2]);
        pk.w = f2bf((v[3]-mean)*rstd*n2g[q*4+3] + n2b[q*4+3]);
        int kg = q >> 1;
        int swz = (kg & 24) | ((kg & 7) ^ (r & 7));
        *(ushort4*)&sNB[r*256 + swz*8 + (q & 1)*4] = pk;
    }
    __syncthreads();

    // ---- H. FFN1: wave w -> 4 n-tiles; h -> sH (frag layout) ----
    {
        U4 wb[8];
        #pragma unroll
        for (int kt = 0; kt < 8; ++kt)
            wb[kt].u4 = *(const uint4*)(w1t + (size_t)((w*4+0)*16 + rr)*256 + kt*32 + kq*8);
        #pragma unroll
        for (int j = 0; j < 4; ++j) {
            int nt = w*4 + j;
            f32x4 acc = {0.f, 0.f, 0.f, 0.f};
            __builtin_amdgcn_s_setprio(1);
            #pragma unroll
            for (int kt = 0; kt < 8; ++kt) {
                int kg = kt*4 + kq;
                int swz = (kg & 24) | ((kg & 7) ^ (rr & 7));
                bf16x8 af = *(const bf16x8*)&sNB[rr*256 + swz*8];
                acc = __builtin_amdgcn_mfma_f32_16x16x32_bf16(af, wb[kt].bv, acc, 0, 0, 0);
            }
            __builtin_amdgcn_s_setprio(0);
            if (j < 3) {
                #pragma unroll
                for (int kt = 0; kt < 8; ++kt)
                    wb[kt].u4 = *(const uint4*)(w1t + (size_t)((nt+1)*16 + rr)*256 + kt*32 + kq*8);
            }
            int n = nt*16 + rr;
            float bias = f1b[n];
            int hkg = n >> 3, hlo = n & 7;
            #pragma unroll
            for (int e = 0; e < 4; ++e) {
                int m = kq*4 + e;
                float v = acc[e] + bias;
                v = 0.5f * v * (1.f + erff(v * 0.70710678118654752f));
                int hswz = (hkg & 120) | ((hkg & 7) ^ (m & 7));
                sH[m*1024 + hswz*8 + hlo] = f2bf(v);
            }
        }
    }
    __syncthreads();

    // ---- I. FFN2: wave w -> 1 n-tile; out = x2 + h @ w2t^T + b2 ----
    {
        U4 qb[8];
        #pragma unroll
        for (int kt = 0; kt < 8; ++kt)
            qb[kt].u4 = *(const uint4*)(w2t + (size_t)(w*16 + rr)*1024 + kt*32 + kq*8);
        f32x4 acc = {0.f, 0.f, 0.f, 0.f};
        #pragma unroll
        for (int grp = 0; grp < 4; ++grp) {
            __builtin_amdgcn_s_setprio(1);
            #pragma unroll
            for (int kt = 0; kt < 8; ++kt) {
                int hkg = (grp*8 + kt)*4 + kq;
                int hswz = (hkg & 120) | ((hkg & 7) ^ (rr & 7));
                bf16x8 af = *(const bf16x8*)&sH[rr*1024 + hswz*8];
                acc = __builtin_amdgcn_mfma_f32_16x16x32_bf16(af, qb[kt].bv, acc, 0, 0, 0);
            }
            __builtin_amdgcn_s_setprio(0);
            if (grp < 3) {
                #pragma unroll
                for (int kt = 0; kt < 8; ++kt)
                    qb[kt].u4 = *(const uint4*)(w2t + (size_t)(w*16 + rr)*1024 + ((grp+1)*8 + kt)*32 + kq*8);
            }
        }
        int col = w*16 + rr;
        float bias = f2b[col];
        #pragma unroll
        for (int e = 0; e < 4; ++e) {
            int row = kq*4 + e;
            outp[((size_t)bb*16 + row)*256 + col] = acc[e] + bias + sFbuf[row][col];
        }
    }
}

extern "C" void kernel_launch(void* const* d_in, const int* in_sizes, int n_in,
                              void* d_out, int out_size, void* d_ws, size_t ws_size,
                              hipStream_t stream)
{
    (void)in_sizes; (void)n_in; (void)out_size;
    const float* x      = (const float*)d_in[0];
    const float* mask   = (const float*)d_in[1];
    const float* B1g    = (const float*)d_in[2];
    const float* B2g    = (const float*)d_in[3];
    const float* absB1  = (const float*)d_in[4];
    const int*   e_i    = (const int*)d_in[5];
    const int*   e_j    = (const int*)d_in[6];
    const int*   t_ij   = (const int*)d_in[7];
    const int*   t_jk   = (const int*)d_in[8];
    const int*   t_ik   = (const int*)d_in[9];
    const float* geom_w = (const float*)d_in[10];
    const float* geom_b = (const float*)d_in[11];
    const float* log_sc = (const float*)d_in[12];
    const float* wv0_w  = (const float*)d_in[13];
    const float* wv0_b  = (const float*)d_in[14];
    const float* wein_w = (const float*)d_in[15];
    const float* wein_b = (const float*)d_in[16];
    const float* out_w  = (const float*)d_in[17];
    const float* out_b  = (const float*)d_in[18];
    const float* n1_g   = (const float*)d_in[19];
    const float* n1_b   = (const float*)d_in[20];
    const float* n2_g   = (const float*)d_in[21];
    const float* n2_b   = (const float*)d_in[22];
    const float* ffn1_w = (const float*)d_in[23];
    const float* ffn1_b = (const float*)d_in[24];
    const float* ffn2_w = (const float*)d_in[25];
    const float* ffn2_b = (const float*)d_in[26];

    float* out = (float*)d_out;
    float* ws  = (float*)d_ws;
    if (ws_size < (size_t)WS_FLOATS * sizeof(float)) return;

    float* ce    = ws + CE_OFF;
    float* bias0 = ws + B0_OFF;
    float* C1    = ws + C1_OFF;
    float* r2    = ws + R2_OFF;
    uint4* ufrag  = (uint4*)(ws + UF_OFF);
    uint4* b1frag = (uint4*)(ws + B1F_OFF);
    uint4* gfrag  = (uint4*)(ws + GF_OFF);
    unsigned short* Qt  = (unsigned short*)(ws + QT_OFF);
    unsigned short* w1t = (unsigned short*)(ws + W1T_OFF);
    unsigned short* w2t = (unsigned short*)(ws + W2T_OFF);

    prep_k<<<653, 256, 0, stream>>>(wv0_w, wein_w, out_w, ffn1_w, ffn2_w,
                                    wv0_b, wein_b, out_b, B1g, absB1, B2g,
                                    Qt, w1t, w2t,
                                    ce, bias0, C1, r2,
                                    ufrag, b1frag, gfrag);
    k_mega<<<256, 1024, 0, stream>>>(x, mask, e_i, e_j, t_ij, t_jk, t_ik,
                                     geom_w, geom_b, log_sc, n1_g, n1_b, n2_g, n2_b,
                                     C1, r2, ufrag, b1frag, gfrag,
                                     Qt, bias0, ce,
                                     w1t, ffn1_b, w2t, ffn2_b, out);
}

// Round 14
// 96.650 us; speedup vs baseline: 1.1841x; 1.1841x over previous
//
#include <hip/hip_runtime.h>
#include <math.h>

#define TAUF  1.0e-4f
#define LNEPS 1.0e-5f

typedef __bf16 bf16x8 __attribute__((ext_vector_type(8)));
typedef float  f32x4  __attribute__((ext_vector_type(4)));

union U4 { uint4 u4; unsigned short us[8]; bf16x8 bv; };

static __device__ __forceinline__ unsigned short f2bf(float f) {
    union { float f; unsigned u; } v; v.f = f;
    unsigned r = v.u + 0x7fffu + ((v.u >> 16) & 1u);
    return (unsigned short)(r >> 16);
}
static __device__ __forceinline__ float bf2f(unsigned short h) {
    union { unsigned u; float f; } v; v.u = ((unsigned)h) << 16;
    return v.f;
}

// ---------------- workspace layout (float offsets, all 16B-aligned) ----------------
static const unsigned CE_OFF   = 0u;         // 768
static const unsigned B0_OFF   = 768u;       // 256
static const unsigned C1_OFF   = 1024u;      // 256
static const unsigned R2_OFF   = 1280u;      // 16
static const unsigned UF_OFF   = 1296u;      // 18*64 uint4 = 4608 f
static const unsigned B1F_OFF  = 5904u;      // 4*64 uint4  = 1024 f
static const unsigned GF_OFF   = 6928u;      // 18*64 uint4 = 4608 f
static const unsigned QT_OFF   = 11536u;     // 393216 bf16 = 196608 f
static const unsigned W1T_OFF  = 208144u;    // 262144 bf16 = 131072 f
static const unsigned W2T_OFF  = 339216u;    // 262144 bf16 = 131072 f
static const unsigned WS_FLOATS = 470288u;   // ~1.9 MB

// ================= prep: ALL x-independent prep in ONE launch (unchanged from R13) =================
__launch_bounds__(256, 2)
__global__ void prep_k(const float* __restrict__ wv0_w, const float* __restrict__ wein_w,
                       const float* __restrict__ out_w,
                       const float* __restrict__ ffn1_w, const float* __restrict__ ffn2_w,
                       const float* __restrict__ wv0_b, const float* __restrict__ wein_b,
                       const float* __restrict__ out_b,
                       const float* __restrict__ B1g, const float* __restrict__ absB1,
                       const float* __restrict__ B2g,
                       unsigned short* __restrict__ Qt,
                       unsigned short* __restrict__ w1t, unsigned short* __restrict__ w2t,
                       float* __restrict__ ce, float* __restrict__ bias0,
                       float* __restrict__ C1, float* __restrict__ r2,
                       uint4* __restrict__ ufrag, uint4* __restrict__ b1frag,
                       uint4* __restrict__ gfrag)
{
    __shared__ float sPool[12800];             // 51.2 KB, aliased per branch
    int b = blockIdx.x, tid = threadIdx.x;
    if (b < 96) {
        float* sTf = sPool;                                     // [64][68] f32
        unsigned short* sBb = (unsigned short*)(sPool + 4352);  // [64][264] bf16
        int by = b >> 2, bx = b & 3;
        int row0 = by * 64, col0 = bx * 64;
        int z = row0 >> 8, o0 = row0 & 255;
        int s = (z < 3) ? z : z - 3;
        const float* Wsel = (z < 3) ? wv0_w : wein_w;
        int lane = tid & 63, w = tid >> 6;
        int rr = lane & 15, kq = lane >> 4;

        #pragma unroll
        for (int i = 0; i < 16; ++i) {
            int idx = i*256 + tid;
            int row = idx >> 6, c4 = idx & 63;
            float4 v = *(const float4*)(Wsel + (size_t)(col0 + row)*768 + s*256 + c4*4);
            ushort4 pk;
            pk.x = f2bf(v.x); pk.y = f2bf(v.y); pk.z = f2bf(v.z); pk.w = f2bf(v.w);
            *(ushort4*)&sBb[row*264 + c4*4] = pk;
        }
        __syncthreads();

        f32x4 acc[4];
        #pragma unroll
        for (int cg = 0; cg < 4; ++cg) acc[cg] = 0.f;
        for (int st = 0; st < 4; ++st) {
            #pragma unroll
            for (int i = 0; i < 4; ++i) {
                int idx = i*256 + tid;
                int dd = idx >> 4, q = idx & 15;
                float4 v = *(const float4*)(out_w + (size_t)(z*256 + st*64 + dd)*256 + o0 + q*4);
                *(float4*)&sTf[dd*68 + q*4] = v;
            }
            __syncthreads();
            #pragma unroll
            for (int ks2 = 0; ks2 < 2; ++ks2) {
                int ks = st*2 + ks2;
                U4 av;
                #pragma unroll
                for (int j = 0; j < 8; ++j)
                    av.us[j] = f2bf(sTf[(ks2*32 + kq*8 + j)*68 + w*16 + rr]);
                #pragma unroll
                for (int cg = 0; cg < 4; ++cg) {
                    bf16x8 bv = *(const bf16x8*)&sBb[(cg*16 + rr)*264 + ks*32 + kq*8];
                    acc[cg] = __builtin_amdgcn_mfma_f32_16x16x32_bf16(av.bv, bv, acc[cg], 0, 0, 0);
                }
            }
            __syncthreads();
        }
        #pragma unroll
        for (int cg = 0; cg < 4; ++cg)
            #pragma unroll
            for (int e = 0; e < 4; ++e) {
                int row = row0 + w*16 + kq*4 + e;
                int col = col0 + cg*16 + rr;
                Qt[(size_t)row*256 + col] = f2bf(acc[cg][e]);
            }
    } else if (b < 352) {
        float (*tile)[33] = (float(*)[33])sPool;
        int bi = b - 96;
        int c0 = (bi & 31) * 32, r0 = (bi >> 5) * 32;
        int tx = tid & 31, ty = tid >> 5;
        #pragma unroll
        for (int i = 0; i < 4; ++i)
            tile[ty + i*8][tx] = ffn1_w[(size_t)(r0 + ty + i*8)*1024 + c0 + tx];
        __syncthreads();
        #pragma unroll
        for (int i = 0; i < 4; ++i)
            w1t[(size_t)(c0 + ty + i*8)*256 + r0 + tx] = f2bf(tile[tx][ty + i*8]);
    } else if (b < 608) {
        float (*tile)[33] = (float(*)[33])sPool;
        int bi = b - 352;
        int c0 = (bi & 7) * 32, r0 = (bi >> 3) * 32;
        int tx = tid & 31, ty = tid >> 5;
        #pragma unroll
        for (int i = 0; i < 4; ++i)
            tile[ty + i*8][tx] = ffn2_w[(size_t)(r0 + ty + i*8)*256 + c0 + tx];
        __syncthreads();
        #pragma unroll
        for (int i = 0; i < 4; ++i)
            w2t[(size_t)(c0 + ty + i*8)*1024 + r0 + tx] = f2bf(tile[tx][ty + i*8]);
    } else if (b < 612) {
        float (*sW)[257] = (float(*)[257])sPool;
        int which = b - 608;
        int o = tid;
        float acc = 0.f;
        if (which == 3) {
            for (int rc = 0; rc < 768; rc += 32) {
                #pragma unroll
                for (int i = 0; i < 32; ++i) sW[i][tid] = out_w[(size_t)(rc+i)*256 + tid];
                __syncthreads();
                #pragma unroll
                for (int i = 0; i < 32; ++i) acc += wv0_b[rc+i] * sW[i][tid];
                __syncthreads();
            }
            bias0[o] = out_b[o] + TAUF * acc;
        } else {
            int base = 768 + which*256;
            for (int rc = 0; rc < 256; rc += 32) {
                #pragma unroll
                for (int i = 0; i < 32; ++i) sW[i][tid] = out_w[(size_t)(base+rc+i)*256 + tid];
                __syncthreads();
                #pragma unroll
                for (int i = 0; i < 32; ++i) acc += wein_b[which*256 + rc+i] * sW[i][tid];
                __syncthreads();
            }
            ce[which*256 + o] = acc;
        }
    } else if (b == 612) {
        int p = tid >> 4, q = tid & 15;
        float c1 = 0.f;
        for (int e = 0; e < 120; ++e) c1 += absB1[p*120+e] * absB1[q*120+e];
        C1[tid] = c1;
        if (tid < 16) {
            float bb = 0.f;
            for (int e = 0; e < 120; ++e) bb += absB1[tid*120+e];
            r2[tid] = bb;
        }
    } else if (b < 631) {
        unsigned short (*sFrag)[8] = (unsigned short(*)[8])sPool;
        int kt = b - 613;
        #pragma unroll
        for (int it = 0; it < 2; ++it) {
            int item = it*256 + tid;
            int lane = item >> 3, j = item & 7;
            int col = lane & 15, kq = lane >> 4;
            int t = kt*32 + kq*8 + j;
            float v = 0.f;
            if (t < 560) {
                for (int e = 0; e < 120; ++e) v += absB1[col*120+e] * B2g[e*560+t];
            } else {
                int p = t - 560;
                for (int e = 0; e < 120; ++e) v += absB1[col*120+e] * B1g[p*120+e];
            }
            sFrag[lane][j] = f2bf(v);
        }
        __syncthreads();
        if (tid < 64) {
            U4 o;
            #pragma unroll
            for (int j = 0; j < 8; ++j) o.us[j] = sFrag[tid][j];
            ufrag[kt*64 + tid] = o.u4;
        }
    } else if (b < 635) {
        if (tid < 64) {
            int lane = tid, col = lane & 15, kq = lane >> 4;
            int kt = b - 631;
            U4 o;
            #pragma unroll
            for (int j = 0; j < 8; ++j) {
                int e = kt*32 + kq*8 + j;
                o.us[j] = f2bf((e < 120) ? B1g[col*120 + e] : 0.f);
            }
            b1frag[kt*64 + lane] = o.u4;
        }
    } else {
        unsigned short (*sFrag)[8] = (unsigned short(*)[8])sPool;
        int kt = b - 635;
        #pragma unroll
        for (int it = 0; it < 2; ++it) {
            int item = it*256 + tid;
            int lane = item >> 3, j = item & 7;
            int col = lane & 15, kq = lane >> 4;
            int t = kt*32 + kq*8 + j;
            float g;
            if (t < 560) {
                float u = 0.f, sgv = 0.f;
                for (int e = 0; e < 120; ++e) {
                    float bv = B2g[e*560+t];
                    u += absB1[col*120+e] * bv;
                    sgv += bv;
                }
                g = sgv * u;
            } else {
                int p = t - 560;
                float c0 = 0.f, r1v = 0.f;
                for (int e = 0; e < 120; ++e) {
                    float bv = B1g[p*120+e];
                    c0 += absB1[col*120+e] * bv;
                    r1v += bv;
                }
                g = c0 * r1v;
            }
            sFrag[lane][j] = f2bf(g);
        }
        __syncthreads();
        if (tid < 64) {
            U4 o;
            #pragma unroll
            for (int j = 0; j < 8; ++j) o.us[j] = sFrag[tid][j];
            gfrag[kt*64 + tid] = o.u4;
        }
    }
}

// ============== k_mega: R13 structure, phase-F register diet (no spill) ==============
__launch_bounds__(1024, 4)
__global__ void k_mega(const float* __restrict__ x, const float* __restrict__ mask,
                       const int* __restrict__ e_i, const int* __restrict__ e_j,
                       const int* __restrict__ t_ij, const int* __restrict__ t_jk,
                       const int* __restrict__ t_ik,
                       const float* __restrict__ geom_w, const float* __restrict__ geom_b,
                       const float* __restrict__ log_sc,
                       const float* __restrict__ n1_g, const float* __restrict__ n1_b,
                       const float* __restrict__ n2g, const float* __restrict__ n2b,
                       const float* __restrict__ C1, const float* __restrict__ r2,
                       const uint4* __restrict__ ufrag, const uint4* __restrict__ b1frag,
                       const uint4* __restrict__ gfrag,
                       const unsigned short* __restrict__ Qt,
                       const float* __restrict__ bias0, const float* __restrict__ ce,
                       const unsigned short* __restrict__ w1t, const float* __restrict__ f1b,
                       const unsigned short* __restrict__ w2t, const float* __restrict__ f2b,
                       float* __restrict__ outp)
{
    __shared__ float sFbuf[16][264];           // xn (phases A-B), then x2 (F-I)
    __shared__ unsigned short sNB[16*256];     // bf16 xn chunks (A-F), then x2n chunks (G-H)
    __shared__ unsigned short sH[16*1024];     // h, frag layout (FFN2 A-frags)
    __shared__ float sP[16][17];
    __shared__ float sW1e[3][128];
    __shared__ float sW2e[3][576];
    __shared__ float sMask[16];
    __shared__ float sO[6*256];
    __shared__ float sRsA[48];

    const int bb = blockIdx.x, tid = threadIdx.x;
    const int w = tid >> 6, lane = tid & 63;
    const int rr = lane & 15, kq = lane >> 4;

    // ---- A. LayerNorm 1: wave w = row w, 64 lanes x 4 elems ----
    {
        const int r = w, q = lane;
        const float* row = x + ((size_t)bb*16 + r)*256 + q*4;
        float4 va = *(const float4*)row;
        float v[4] = {va.x, va.y, va.z, va.w};
        float sum = v[0]+v[1]+v[2]+v[3];
        float ss  = v[0]*v[0]+v[1]*v[1]+v[2]*v[2]+v[3]*v[3];
        #pragma unroll
        for (int o = 32; o; o >>= 1) { sum += __shfl_xor(sum, o); ss += __shfl_xor(ss, o); }
        float mean = sum * (1.f/256.f);
        float rstd = rsqrtf(ss*(1.f/256.f) - mean*mean + LNEPS);
        ushort4 pk;
        float xv0 = (v[0]-mean)*rstd*n1_g[q*4+0] + n1_b[q*4+0];
        float xv1 = (v[1]-mean)*rstd*n1_g[q*4+1] + n1_b[q*4+1];
        float xv2 = (v[2]-mean)*rstd*n1_g[q*4+2] + n1_b[q*4+2];
        float xv3 = (v[3]-mean)*rstd*n1_g[q*4+3] + n1_b[q*4+3];
        sFbuf[r][q*4+0] = xv0; sFbuf[r][q*4+1] = xv1;
        sFbuf[r][q*4+2] = xv2; sFbuf[r][q*4+3] = xv3;
        pk.x = f2bf(xv0); pk.y = f2bf(xv1); pk.z = f2bf(xv2); pk.w = f2bf(xv3);
        int kg = q >> 1;
        int swz = (kg & 24) | ((kg & 7) ^ (r & 7));
        *(ushort4*)&sNB[r*256 + swz*8 + (q & 1)*4] = pk;
        if (tid < 16) sMask[tid] = mask[bb*16 + tid];
    }
    __syncthreads();

    // ---- B. P = xn @ geom_w + geom_b: (r, g, quarter), global geom_w ----
    {
        const int r = w, g = (lane >> 2) & 15, quarter = lane & 3;
        const int cb = quarter * 64;
        float a0 = 0.f, a1 = 0.f, a2 = 0.f, a3 = 0.f;
        #pragma unroll
        for (int c = 0; c < 64; c += 4) {
            float4 xv = *(const float4*)&sFbuf[r][cb + c];
            a0 += xv.x * geom_w[(cb+c+0)*16 + g];
            a1 += xv.y * geom_w[(cb+c+1)*16 + g];
            a2 += xv.z * geom_w[(cb+c+2)*16 + g];
            a3 += xv.w * geom_w[(cb+c+3)*16 + g];
        }
        float p = (a0+a1) + (a2+a3);
        p += __shfl_xor(p, 1);
        p += __shfl_xor(p, 2);
        if (quarter == 0) sP[r][g] = p + geom_b[g];
    }
    __syncthreads();

    // ---- C. W1: e = tid>>3, s = tid&7 ----
    {
        int e = tid >> 3, s = tid & 7;
        if (e < 120 && s < 3) {
            int i0 = e_i[e], j0 = e_j[e];
            float d2 = 0.f;
            #pragma unroll
            for (int m = 0; m < 16; ++m) { float dd = sP[i0][m] - sP[j0][m]; d2 += dd*dd; }
            float mm = sMask[i0]*sMask[j0];
            d2 *= mm*mm;
            float sc = expf(log_sc[s]);
            sW1e[s][e] = expf(-d2/(2.f*sc*sc + 1e-8f)) * mm;
        }
        if (tid < 24) sW1e[tid >> 3][120 + (tid & 7)] = 0.f;
    }
    __syncthreads();

    // ---- D. W2 + mask extension ----
    if (tid < 560) {
        int t = tid;
        int a = t_ij[t], b2 = t_jk[t], c2 = t_ik[t];
        #pragma unroll
        for (int s = 0; s < 3; ++s) sW2e[s][t] = sW1e[s][a]*sW1e[s][b2]*sW1e[s][c2];
    }
    if (tid < 48) sW2e[tid >> 4][560 + (tid & 15)] = sMask[tid & 15];
    __syncthreads();

    // ---- E. waves 0-2: edge O; wave 3: node O; wave 4: rsA via gfrag MFMA ----
    if (w < 3) {
        int s = w;
        f32x4 acc = {0.f, 0.f, 0.f, 0.f};
        __builtin_amdgcn_s_setprio(1);
        #pragma unroll 3
        for (int kt = 0; kt < 18; ++kt) {
            U4 ub; ub.u4 = ufrag[kt*64 + lane];
            const float4* w4 = (const float4*)&sW2e[s][kt*32 + kq*8];
            float4 wa = w4[0], wb = w4[1];
            U4 av;
            av.us[0] = f2bf(wa.x * bf2f(ub.us[0]));
            av.us[1] = f2bf(wa.y * bf2f(ub.us[1]));
            av.us[2] = f2bf(wa.z * bf2f(ub.us[2]));
            av.us[3] = f2bf(wa.w * bf2f(ub.us[3]));
            av.us[4] = f2bf(wb.x * bf2f(ub.us[4]));
            av.us[5] = f2bf(wb.y * bf2f(ub.us[5]));
            av.us[6] = f2bf(wb.z * bf2f(ub.us[6]));
            av.us[7] = f2bf(wb.w * bf2f(ub.us[7]));
            acc = __builtin_amdgcn_mfma_f32_16x16x32_bf16(av.bv, ub.bv, acc, 0, 0, 0);
        }
        __builtin_amdgcn_s_setprio(0);
        #pragma unroll
        for (int e = 0; e < 4; ++e) {
            int row = kq*4 + e;
            sO[(3+s)*256 + row*16 + rr] = acc[e] + TAUF*C1[row*16 + rr];
        }
    } else if (w == 3) {
        f32x4 acc3[3];
        acc3[0] = 0.f; acc3[1] = 0.f; acc3[2] = 0.f;
        __builtin_amdgcn_s_setprio(1);
        #pragma unroll
        for (int kt = 0; kt < 4; ++kt) {
            U4 ub; ub.u4 = b1frag[kt*64 + lane];
            float uf[8];
            #pragma unroll
            for (int j = 0; j < 8; ++j) uf[j] = bf2f(ub.us[j]);
            #pragma unroll
            for (int s = 0; s < 3; ++s) {
                const float4* w4 = (const float4*)&sW1e[s][kt*32 + kq*8];
                float4 wa = w4[0], wb = w4[1];
                U4 av;
                av.us[0] = f2bf(wa.x * uf[0]);
                av.us[1] = f2bf(wa.y * uf[1]);
                av.us[2] = f2bf(wa.z * uf[2]);
                av.us[3] = f2bf(wa.w * uf[3]);
                av.us[4] = f2bf(wb.x * uf[4]);
                av.us[5] = f2bf(wb.y * uf[5]);
                av.us[6] = f2bf(wb.z * uf[6]);
                av.us[7] = f2bf(wb.w * uf[7]);
                acc3[s] = __builtin_amdgcn_mfma_f32_16x16x32_bf16(av.bv, ub.bv, acc3[s], 0, 0, 0);
            }
        }
        __builtin_amdgcn_s_setprio(0);
        #pragma unroll
        for (int s = 0; s < 3; ++s)
            #pragma unroll
            for (int e = 0; e < 4; ++e) {
                int row = kq*4 + e;
                sO[s*256 + row*16 + rr] = acc3[s][e] + ((row == rr) ? TAUF : 0.f);
            }
    } else if (w == 4) {
        f32x4 acc = {0.f, 0.f, 0.f, 0.f};
        int srow = (rr < 3) ? rr : 0;
        __builtin_amdgcn_s_setprio(1);
        #pragma unroll 3
        for (int kt = 0; kt < 18; ++kt) {
            U4 gb; gb.u4 = gfrag[kt*64 + lane];
            const float4* w4 = (const float4*)&sW2e[srow][kt*32 + kq*8];
            float4 wa = w4[0], wb = w4[1];
            U4 av;
            av.us[0] = f2bf(wa.x); av.us[1] = f2bf(wa.y);
            av.us[2] = f2bf(wa.z); av.us[3] = f2bf(wa.w);
            av.us[4] = f2bf(wb.x); av.us[5] = f2bf(wb.y);
            av.us[6] = f2bf(wb.z); av.us[7] = f2bf(wb.w);
            acc = __builtin_amdgcn_mfma_f32_16x16x32_bf16(av.bv, gb.bv, acc, 0, 0, 0);
        }
        __builtin_amdgcn_s_setprio(0);
        if (kq == 0) {
            #pragma unroll
            for (int e = 0; e < 3; ++e)
                sRsA[e*16 + rr] = acc[e] + TAUF * r2[rr];
        }
    }
    __syncthreads();

    // ---- F. wave-local Y-GEMM + in-register O-contraction (no barriers, no sYb),
    //         register-dieted: 4-deep qf, no xr prefetch ----
    {
        const int col = w*16 + rr;
        float accP[16];
        #pragma unroll
        for (int k = 0; k < 16; ++k) accP[k] = 0.f;
        for (int blk = 0; blk < 6; ++blk) {
            f32x4 ya = {0.f, 0.f, 0.f, 0.f};
            #pragma unroll
            for (int half = 0; half < 2; ++half) {
                U4 qf[4];
                #pragma unroll
                for (int kt = 0; kt < 4; ++kt)
                    qf[kt].u4 = *(const uint4*)(Qt + ((size_t)(blk*256 + w*16 + rr))*256 + (half*4 + kt)*32 + kq*8);
                __builtin_amdgcn_s_setprio(1);
                #pragma unroll
                for (int kt = 0; kt < 4; ++kt) {
                    int kg = (half*4 + kt)*4 + kq;
                    int swz = (kg & 24) | ((kg & 7) ^ (rr & 7));
                    bf16x8 af = *(const bf16x8*)&sNB[rr*256 + swz*8];
                    ya = __builtin_amdgcn_mfma_f32_16x16x32_bf16(af, qf[kt].bv, ya, 0, 0, 0);
                }
                __builtin_amdgcn_s_setprio(0);
            }
            // accP[k] += O[k][kq*4+e] * ya[e]  (float4 broadcast LDS reads)
            #pragma unroll
            for (int k = 0; k < 16; ++k) {
                float4 ov = *(const float4*)&sO[blk*256 + k*16 + kq*4];
                accP[k] += ov.x*ya[0] + ov.y*ya[1] + ov.z*ya[2] + ov.w*ya[3];
            }
        }
        // reduce the 4 kq-group partials (lane bits 4-5)
        #pragma unroll
        for (int k = 0; k < 16; ++k) {
            accP[k] += __shfl_xor(accP[k], 16);
            accP[k] += __shfl_xor(accP[k], 32);
        }
        float b0v = bias0[col], c0v = ce[col], c1v = ce[256+col], c2v = ce[512+col];
        #pragma unroll
        for (int e = 0; e < 4; ++e) {
            int k = kq*4 + e;
            float v = accP[k] + b0v
                    + sRsA[     k] * c0v
                    + sRsA[16 + k] * c1v
                    + sRsA[32 + k] * c2v
                    + x[((size_t)bb*16 + k)*256 + col];
            sFbuf[k][col] = v;       // x2 (xn dead)
        }
    }
    __syncthreads();

    // ---- G. LN2 -> sNB (x2n bf16 chunks) ----
    {
        const int r = w, q = lane;
        float v[4];
        v[0] = sFbuf[r][q*4+0]; v[1] = sFbuf[r][q*4+1];
        v[2] = sFbuf[r][q*4+2]; v[3] = sFbuf[r][q*4+3];
        float sum = v[0]+v[1]+v[2]+v[3];
        float ss  = v[0]*v[0]+v[1]*v[1]+v[2]*v[2]+v[3]*v[3];
        #pragma unroll
        for (int o = 32; o; o >>= 1) { sum += __shfl_xor(sum, o); ss += __shfl_xor(ss, o); }
        float mean = sum * (1.f/256.f);
        float rstd = rsqrtf(ss*(1.f/256.f) - mean*mean + LNEPS);
        ushort4 pk;
        pk.x = f2bf((v[0]-mean)*rstd*n2g[q*4+0] + n2b[q*4+0]);
        pk.y = f2bf((v[1]-mean)*rstd*n2g[q*4+1] + n2b[q*4+1]);
        pk.z = f2bf((v[2]-mean)*rstd*n2g[q*4+2] + n2b[q*4+2]);
        pk.w = f2bf((v[3]-mean)*rstd*n2g[q*4+3] + n2b[q*4+3]);
        int kg = q >> 1;
        int swz = (kg & 24) | ((kg & 7) ^ (r & 7));
        *(ushort4*)&sNB[r*256 + swz*8 + (q & 1)*4] = pk;
    }
    __syncthreads();

    // ---- H. FFN1: wave w -> 4 n-tiles; h -> sH (frag layout) ----
    {
        U4 wb[8];
        #pragma unroll
        for (int kt = 0; kt < 8; ++kt)
            wb[kt].u4 = *(const uint4*)(w1t + (size_t)((w*4+0)*16 + rr)*256 + kt*32 + kq*8);
        #pragma unroll
        for (int j = 0; j < 4; ++j) {
            int nt = w*4 + j;
            f32x4 acc = {0.f, 0.f, 0.f, 0.f};
            __builtin_amdgcn_s_setprio(1);
            #pragma unroll
            for (int kt = 0; kt < 8; ++kt) {
                int kg = kt*4 + kq;
                int swz = (kg & 24) | ((kg & 7) ^ (rr & 7));
                bf16x8 af = *(const bf16x8*)&sNB[rr*256 + swz*8];
                acc = __builtin_amdgcn_mfma_f32_16x16x32_bf16(af, wb[kt].bv, acc, 0, 0, 0);
            }
            __builtin_amdgcn_s_setprio(0);
            if (j < 3) {
                #pragma unroll
                for (int kt = 0; kt < 8; ++kt)
                    wb[kt].u4 = *(const uint4*)(w1t + (size_t)((nt+1)*16 + rr)*256 + kt*32 + kq*8);
            }
            int n = nt*16 + rr;
            float bias = f1b[n];
            int hkg = n >> 3, hlo = n & 7;
            #pragma unroll
            for (int e = 0; e < 4; ++e) {
                int m = kq*4 + e;
                float v = acc[e] + bias;
                v = 0.5f * v * (1.f + erff(v * 0.70710678118654752f));
                int hswz = (hkg & 120) | ((hkg & 7) ^ (m & 7));
                sH[m*1024 + hswz*8 + hlo] = f2bf(v);
            }
        }
    }
    __syncthreads();

    // ---- I. FFN2: wave w -> 1 n-tile; out = x2 + h @ w2t^T + b2 ----
    {
        U4 qb[8];
        #pragma unroll
        for (int kt = 0; kt < 8; ++kt)
            qb[kt].u4 = *(const uint4*)(w2t + (size_t)(w*16 + rr)*1024 + kt*32 + kq*8);
        f32x4 acc = {0.f, 0.f, 0.f, 0.f};
        #pragma unroll
        for (int grp = 0; grp < 4; ++grp) {
            __builtin_amdgcn_s_setprio(1);
            #pragma unroll
            for (int kt = 0; kt < 8; ++kt) {
                int hkg = (grp*8 + kt)*4 + kq;
                int hswz = (hkg & 120) | ((hkg & 7) ^ (rr & 7));
                bf16x8 af = *(const bf16x8*)&sH[rr*1024 + hswz*8];
                acc = __builtin_amdgcn_mfma_f32_16x16x32_bf16(af, qb[kt].bv, acc, 0, 0, 0);
            }
            __builtin_amdgcn_s_setprio(0);
            if (grp < 3) {
                #pragma unroll
                for (int kt = 0; kt < 8; ++kt)
                    qb[kt].u4 = *(const uint4*)(w2t + (size_t)(w*16 + rr)*1024 + ((grp+1)*8 + kt)*32 + kq*8);
            }
        }
        int col = w*16 + rr;
        float bias = f2b[col];
        #pragma unroll
        for (int e = 0; e < 4; ++e) {
            int row = kq*4 + e;
            outp[((size_t)bb*16 + row)*256 + col] = acc[e] + bias + sFbuf[row][col];
        }
    }
}

extern "C" void kernel_launch(void* const* d_in, const int* in_sizes, int n_in,
                              void* d_out, int out_size, void* d_ws, size_t ws_size,
                              hipStream_t stream)
{
    (void)in_sizes; (void)n_in; (void)out_size;
    const float* x      = (const float*)d_in[0];
    const float* mask   = (const float*)d_in[1];
    const float* B1g    = (const float*)d_in[2];
    const float* B2g    = (const float*)d_in[3];
    const float* absB1  = (const float*)d_in[4];
    const int*   e_i    = (const int*)d_in[5];
    const int*   e_j    = (const int*)d_in[6];
    const int*   t_ij   = (const int*)d_in[7];
    const int*   t_jk   = (const int*)d_in[8];
    const int*   t_ik   = (const int*)d_in[9];
    const float* geom_w = (const float*)d_in[10];
    const float* geom_b = (const float*)d_in[11];
    const float* log_sc = (const float*)d_in[12];
    const float* wv0_w  = (const float*)d_in[13];
    const float* wv0_b  = (const float*)d_in[14];
    const float* wein_w = (const float*)d_in[15];
    const float* wein_b = (const float*)d_in[16];
    const float* out_w  = (const float*)d_in[17];
    const float* out_b  = (const float*)d_in[18];
    const float* n1_g   = (const float*)d_in[19];
    const float* n1_b   = (const float*)d_in[20];
    const float* n2_g   = (const float*)d_in[21];
    const float* n2_b   = (const float*)d_in[22];
    const float* ffn1_w = (const float*)d_in[23];
    const float* ffn1_b = (const float*)d_in[24];
    const float* ffn2_w = (const float*)d_in[25];
    const float* ffn2_b = (const float*)d_in[26];

    float* out = (float*)d_out;
    float* ws  = (float*)d_ws;
    if (ws_size < (size_t)WS_FLOATS * sizeof(float)) return;

    float* ce    = ws + CE_OFF;
    float* bias0 = ws + B0_OFF;
    float* C1    = ws + C1_OFF;
    float* r2    = ws + R2_OFF;
    uint4* ufrag  = (uint4*)(ws + UF_OFF);
    uint4* b1frag = (uint4*)(ws + B1F_OFF);
    uint4* gfrag  = (uint4*)(ws + GF_OFF);
    unsigned short* Qt  = (unsigned short*)(ws + QT_OFF);
    unsigned short* w1t = (unsigned short*)(ws + W1T_OFF);
    unsigned short* w2t = (unsigned short*)(ws + W2T_OFF);

    prep_k<<<653, 256, 0, stream>>>(wv0_w, wein_w, out_w, ffn1_w, ffn2_w,
                                    wv0_b, wein_b, out_b, B1g, absB1, B2g,
                                    Qt, w1t, w2t,
                                    ce, bias0, C1, r2,
                                    ufrag, b1frag, gfrag);
    k_mega<<<256, 1024, 0, stream>>>(x, mask, e_i, e_j, t_ij, t_jk, t_ik,
                                     geom_w, geom_b, log_sc, n1_g, n1_b, n2_g, n2_b,
                                     C1, r2, ufrag, b1frag, gfrag,
                                     Qt, bias0, ce,
                                     w1t, ffn1_b, w2t, ffn2_b, out);
}

// Round 15
// 87.951 us; speedup vs baseline: 1.3013x; 1.0989x over previous
//
#include <hip/hip_runtime.h>
#include <math.h>

#define TAUF  1.0e-4f
#define LNEPS 1.0e-5f

typedef __bf16 bf16x8 __attribute__((ext_vector_type(8)));
typedef float  f32x4  __attribute__((ext_vector_type(4)));

union U4 { uint4 u4; unsigned short us[8]; bf16x8 bv; };

static __device__ __forceinline__ unsigned short f2bf(float f) {
    union { float f; unsigned u; } v; v.f = f;
    unsigned r = v.u + 0x7fffu + ((v.u >> 16) & 1u);
    return (unsigned short)(r >> 16);
}
static __device__ __forceinline__ float bf2f(unsigned short h) {
    union { unsigned u; float f; } v; v.u = ((unsigned)h) << 16;
    return v.f;
}

// ---------------- workspace layout (float offsets, all 16B-aligned) ----------------
static const unsigned CE_OFF   = 0u;         // 768
static const unsigned B0_OFF   = 768u;       // 256
static const unsigned C1_OFF   = 1024u;      // 256
static const unsigned R2_OFF   = 1280u;      // 16
static const unsigned UF_OFF   = 1296u;      // 18*64 uint4 = 4608 f
static const unsigned B1F_OFF  = 5904u;      // 4*64 uint4  = 1024 f
static const unsigned GF_OFF   = 6928u;      // 18*64 uint4 = 4608 f
static const unsigned QT_OFF   = 11536u;     // 393216 bf16 = 196608 f
static const unsigned W1T_OFF  = 208144u;    // 262144 bf16 = 131072 f
static const unsigned W2T_OFF  = 339216u;    // 262144 bf16 = 131072 f
static const unsigned WS_FLOATS = 470288u;   // ~1.9 MB

// ================= prep: consolidated (grid 269) =================
// b <  96 : Qt MFMA GEMM (both operands LDS-staged)
// b < 160 : transpose ffn1_w -> w1t (4 tiles/block)
// b < 224 : transpose ffn2_w -> w2t (4 tiles/block)
// b < 228 : bias folds (ce, bias0)
// b = 228 : C1, r2
// b < 247 : ufrag ; b < 251 : b1frag ; b < 269 : gfrag
__launch_bounds__(256, 2)
__global__ void prep_k(const float* __restrict__ wv0_w, const float* __restrict__ wein_w,
                       const float* __restrict__ out_w,
                       const float* __restrict__ ffn1_w, const float* __restrict__ ffn2_w,
                       const float* __restrict__ wv0_b, const float* __restrict__ wein_b,
                       const float* __restrict__ out_b,
                       const float* __restrict__ B1g, const float* __restrict__ absB1,
                       const float* __restrict__ B2g,
                       unsigned short* __restrict__ Qt,
                       unsigned short* __restrict__ w1t, unsigned short* __restrict__ w2t,
                       float* __restrict__ ce, float* __restrict__ bias0,
                       float* __restrict__ C1, float* __restrict__ r2,
                       uint4* __restrict__ ufrag, uint4* __restrict__ b1frag,
                       uint4* __restrict__ gfrag)
{
    __shared__ float sPool[12800];
    int b = blockIdx.x, tid = threadIdx.x;
    if (b < 96) {
        float* sTf = sPool;                                     // [64][68] f32
        unsigned short* sBb = (unsigned short*)(sPool + 4352);  // [64][264] bf16
        int by = b >> 2, bx = b & 3;
        int row0 = by * 64, col0 = bx * 64;
        int z = row0 >> 8, o0 = row0 & 255;
        int s = (z < 3) ? z : z - 3;
        const float* Wsel = (z < 3) ? wv0_w : wein_w;
        int lane = tid & 63, w = tid >> 6;
        int rr = lane & 15, kq = lane >> 4;

        #pragma unroll
        for (int i = 0; i < 16; ++i) {
            int idx = i*256 + tid;
            int row = idx >> 6, c4 = idx & 63;
            float4 v = *(const float4*)(Wsel + (size_t)(col0 + row)*768 + s*256 + c4*4);
            ushort4 pk;
            pk.x = f2bf(v.x); pk.y = f2bf(v.y); pk.z = f2bf(v.z); pk.w = f2bf(v.w);
            *(ushort4*)&sBb[row*264 + c4*4] = pk;
        }
        __syncthreads();

        f32x4 acc[4];
        #pragma unroll
        for (int cg = 0; cg < 4; ++cg) acc[cg] = 0.f;
        for (int st = 0; st < 4; ++st) {
            #pragma unroll
            for (int i = 0; i < 4; ++i) {
                int idx = i*256 + tid;
                int dd = idx >> 4, q = idx & 15;
                float4 v = *(const float4*)(out_w + (size_t)(z*256 + st*64 + dd)*256 + o0 + q*4);
                *(float4*)&sTf[dd*68 + q*4] = v;
            }
            __syncthreads();
            #pragma unroll
            for (int ks2 = 0; ks2 < 2; ++ks2) {
                int ks = st*2 + ks2;
                U4 av;
                #pragma unroll
                for (int j = 0; j < 8; ++j)
                    av.us[j] = f2bf(sTf[(ks2*32 + kq*8 + j)*68 + w*16 + rr]);
                #pragma unroll
                for (int cg = 0; cg < 4; ++cg) {
                    bf16x8 bv = *(const bf16x8*)&sBb[(cg*16 + rr)*264 + ks*32 + kq*8];
                    acc[cg] = __builtin_amdgcn_mfma_f32_16x16x32_bf16(av.bv, bv, acc[cg], 0, 0, 0);
                }
            }
            __syncthreads();
        }
        #pragma unroll
        for (int cg = 0; cg < 4; ++cg)
            #pragma unroll
            for (int e = 0; e < 4; ++e) {
                int row = row0 + w*16 + kq*4 + e;
                int col = col0 + cg*16 + rr;
                Qt[(size_t)row*256 + col] = f2bf(acc[cg][e]);
            }
    } else if (b < 160) {
        float (*tile)[33] = (float(*)[33])sPool;
        int tx = tid & 31, ty = tid >> 5;
        for (int ti = 0; ti < 4; ++ti) {
            int bi = (b - 96)*4 + ti;
            int c0 = (bi & 31) * 32, r0 = (bi >> 5) * 32;
            if (ti) __syncthreads();
            #pragma unroll
            for (int i = 0; i < 4; ++i)
                tile[ty + i*8][tx] = ffn1_w[(size_t)(r0 + ty + i*8)*1024 + c0 + tx];
            __syncthreads();
            #pragma unroll
            for (int i = 0; i < 4; ++i)
                w1t[(size_t)(c0 + ty + i*8)*256 + r0 + tx] = f2bf(tile[tx][ty + i*8]);
        }
    } else if (b < 224) {
        float (*tile)[33] = (float(*)[33])sPool;
        int tx = tid & 31, ty = tid >> 5;
        for (int ti = 0; ti < 4; ++ti) {
            int bi = (b - 160)*4 + ti;
            int c0 = (bi & 7) * 32, r0 = (bi >> 3) * 32;
            if (ti) __syncthreads();
            #pragma unroll
            for (int i = 0; i < 4; ++i)
                tile[ty + i*8][tx] = ffn2_w[(size_t)(r0 + ty + i*8)*256 + c0 + tx];
            __syncthreads();
            #pragma unroll
            for (int i = 0; i < 4; ++i)
                w2t[(size_t)(c0 + ty + i*8)*1024 + r0 + tx] = f2bf(tile[tx][ty + i*8]);
        }
    } else if (b < 228) {
        float (*sW)[257] = (float(*)[257])sPool;
        int which = b - 224;
        int o = tid;
        float acc = 0.f;
        if (which == 3) {
            for (int rc = 0; rc < 768; rc += 32) {
                #pragma unroll
                for (int i = 0; i < 32; ++i) sW[i][tid] = out_w[(size_t)(rc+i)*256 + tid];
                __syncthreads();
                #pragma unroll
                for (int i = 0; i < 32; ++i) acc += wv0_b[rc+i] * sW[i][tid];
                __syncthreads();
            }
            bias0[o] = out_b[o] + TAUF * acc;
        } else {
            int base = 768 + which*256;
            for (int rc = 0; rc < 256; rc += 32) {
                #pragma unroll
                for (int i = 0; i < 32; ++i) sW[i][tid] = out_w[(size_t)(base+rc+i)*256 + tid];
                __syncthreads();
                #pragma unroll
                for (int i = 0; i < 32; ++i) acc += wein_b[which*256 + rc+i] * sW[i][tid];
                __syncthreads();
            }
            ce[which*256 + o] = acc;
        }
    } else if (b == 228) {
        int p = tid >> 4, q = tid & 15;
        float c1 = 0.f;
        for (int e = 0; e < 120; ++e) c1 += absB1[p*120+e] * absB1[q*120+e];
        C1[tid] = c1;
        if (tid < 16) {
            float bb = 0.f;
            for (int e = 0; e < 120; ++e) bb += absB1[tid*120+e];
            r2[tid] = bb;
        }
    } else if (b < 247) {
        unsigned short (*sFrag)[8] = (unsigned short(*)[8])sPool;
        int kt = b - 229;
        #pragma unroll
        for (int it = 0; it < 2; ++it) {
            int item = it*256 + tid;
            int lane = item >> 3, j = item & 7;
            int col = lane & 15, kq = lane >> 4;
            int t = kt*32 + kq*8 + j;
            float v = 0.f;
            if (t < 560) {
                for (int e = 0; e < 120; ++e) v += absB1[col*120+e] * B2g[e*560+t];
            } else {
                int p = t - 560;
                for (int e = 0; e < 120; ++e) v += absB1[col*120+e] * B1g[p*120+e];
            }
            sFrag[lane][j] = f2bf(v);
        }
        __syncthreads();
        if (tid < 64) {
            U4 o;
            #pragma unroll
            for (int j = 0; j < 8; ++j) o.us[j] = sFrag[tid][j];
            ufrag[kt*64 + tid] = o.u4;
        }
    } else if (b < 251) {
        if (tid < 64) {
            int lane = tid, col = lane & 15, kq = lane >> 4;
            int kt = b - 247;
            U4 o;
            #pragma unroll
            for (int j = 0; j < 8; ++j) {
                int e = kt*32 + kq*8 + j;
                o.us[j] = f2bf((e < 120) ? B1g[col*120 + e] : 0.f);
            }
            b1frag[kt*64 + lane] = o.u4;
        }
    } else {
        unsigned short (*sFrag)[8] = (unsigned short(*)[8])sPool;
        int kt = b - 251;
        #pragma unroll
        for (int it = 0; it < 2; ++it) {
            int item = it*256 + tid;
            int lane = item >> 3, j = item & 7;
            int col = lane & 15, kq = lane >> 4;
            int t = kt*32 + kq*8 + j;
            float g;
            if (t < 560) {
                float u = 0.f, sgv = 0.f;
                for (int e = 0; e < 120; ++e) {
                    float bv = B2g[e*560+t];
                    u += absB1[col*120+e] * bv;
                    sgv += bv;
                }
                g = sgv * u;
            } else {
                int p = t - 560;
                float c0 = 0.f, r1v = 0.f;
                for (int e = 0; e < 120; ++e) {
                    float bv = B1g[p*120+e];
                    c0 += absB1[col*120+e] * bv;
                    r1v += bv;
                }
                g = c0 * r1v;
            }
            sFrag[lane][j] = f2bf(g);
        }
        __syncthreads();
        if (tid < 64) {
            U4 o;
            #pragma unroll
            for (int j = 0; j < 8; ++j) o.us[j] = sFrag[tid][j];
            gfrag[kt*64 + tid] = o.u4;
        }
    }
}

// ============== k_mega: async wave-teams — geo (w0-4, LDS-flag sync) || Y-GEMM (w5-15) ==============
__launch_bounds__(1024, 4)
__global__ void k_mega(const float* __restrict__ x, const float* __restrict__ mask,
                       const int* __restrict__ e_i, const int* __restrict__ e_j,
                       const int* __restrict__ t_ij, const int* __restrict__ t_jk,
                       const int* __restrict__ t_ik,
                       const float* __restrict__ geom_w, const float* __restrict__ geom_b,
                       const float* __restrict__ log_sc,
                       const float* __restrict__ n1_g, const float* __restrict__ n1_b,
                       const float* __restrict__ n2g, const float* __restrict__ n2b,
                       const float* __restrict__ C1, const float* __restrict__ r2,
                       const uint4* __restrict__ ufrag, const uint4* __restrict__ b1frag,
                       const uint4* __restrict__ gfrag,
                       const unsigned short* __restrict__ Qt,
                       const float* __restrict__ bias0, const float* __restrict__ ce,
                       const unsigned short* __restrict__ w1t, const float* __restrict__ f1b,
                       const unsigned short* __restrict__ w2t, const float* __restrict__ f2b,
                       float* __restrict__ outp)
{
    __shared__ float sFbuf[16][264];           // xn (A..B), then x2 (F..I)
    __shared__ unsigned short sNB[16*256];     // bf16 xn chunks (A..F), then x2n (G,H)
    __shared__ unsigned short sH[16*1024];     // h, frag layout
    __shared__ float sP[16][17];
    __shared__ float sW1e[3][128];
    __shared__ float sW2e[3][576];
    __shared__ float sMask[16];
    __shared__ float sO[6*256];
    __shared__ float sRsA[48];
    __shared__ int sCnt[4];
    __shared__ int sFlagO;

    const int bb = blockIdx.x, tid = threadIdx.x;
    const int w = tid >> 6, lane = tid & 63;
    const int rr = lane & 15, kq = lane >> 4;

    // ---- A. LayerNorm 1 (all waves) + flag init ----
    {
        if (tid < 4) sCnt[tid] = 0;
        if (tid == 4) sFlagO = 0;
        const int r = w, q = lane;
        const float* row = x + ((size_t)bb*16 + r)*256 + q*4;
        float4 va = *(const float4*)row;
        float v[4] = {va.x, va.y, va.z, va.w};
        float sum = v[0]+v[1]+v[2]+v[3];
        float ss  = v[0]*v[0]+v[1]*v[1]+v[2]*v[2]+v[3]*v[3];
        #pragma unroll
        for (int o = 32; o; o >>= 1) { sum += __shfl_xor(sum, o); ss += __shfl_xor(ss, o); }
        float mean = sum * (1.f/256.f);
        float rstd = rsqrtf(ss*(1.f/256.f) - mean*mean + LNEPS);
        ushort4 pk;
        float xv0 = (v[0]-mean)*rstd*n1_g[q*4+0] + n1_b[q*4+0];
        float xv1 = (v[1]-mean)*rstd*n1_g[q*4+1] + n1_b[q*4+1];
        float xv2 = (v[2]-mean)*rstd*n1_g[q*4+2] + n1_b[q*4+2];
        float xv3 = (v[3]-mean)*rstd*n1_g[q*4+3] + n1_b[q*4+3];
        sFbuf[r][q*4+0] = xv0; sFbuf[r][q*4+1] = xv1;
        sFbuf[r][q*4+2] = xv2; sFbuf[r][q*4+3] = xv3;
        pk.x = f2bf(xv0); pk.y = f2bf(xv1); pk.z = f2bf(xv2); pk.w = f2bf(xv3);
        int kg = q >> 1;
        int swz = (kg & 24) | ((kg & 7) ^ (r & 7));
        *(ushort4*)&sNB[r*256 + swz*8 + (q & 1)*4] = pk;
        if (tid < 16) sMask[tid] = mask[bb*16 + tid];
    }
    __syncthreads();                                     // barrier #1

    auto team_bar = [&](int idx) {
        if ((tid & 63) == 0)
            __hip_atomic_fetch_add(&sCnt[idx], 1, __ATOMIC_ACQ_REL, __HIP_MEMORY_SCOPE_WORKGROUP);
        while (__hip_atomic_load(&sCnt[idx], __ATOMIC_ACQUIRE, __HIP_MEMORY_SCOPE_WORKGROUP) < 5)
            __builtin_amdgcn_s_sleep(1);
    };

    if (w < 5) {
        // ================== GEO TEAM (waves 0-4) ==================
        // B. P = xn @ geom_w + geom_b (256 threads, full dot)
        if (tid < 256) {
            int r = tid >> 4, g = tid & 15;
            float a0 = 0.f, a1 = 0.f, a2 = 0.f, a3 = 0.f;
            for (int c = 0; c < 256; c += 4) {
                float4 xv = *(const float4*)&sFbuf[r][c];
                a0 += xv.x * geom_w[(c+0)*16 + g];
                a1 += xv.y * geom_w[(c+1)*16 + g];
                a2 += xv.z * geom_w[(c+2)*16 + g];
                a3 += xv.w * geom_w[(c+3)*16 + g];
            }
            sP[r][g] = (a0+a1) + (a2+a3) + geom_b[g];
        }
        team_bar(0);
        // C. W1 (thread e < 120, all 3 scales)
        if (tid < 120) {
            int e = tid, i0 = e_i[e], j0 = e_j[e];
            float d2 = 0.f;
            #pragma unroll
            for (int m = 0; m < 16; ++m) { float dd = sP[i0][m] - sP[j0][m]; d2 += dd*dd; }
            float mm = sMask[i0]*sMask[j0];
            d2 *= mm*mm;
            #pragma unroll
            for (int s = 0; s < 3; ++s) {
                float sc = expf(log_sc[s]);
                sW1e[s][e] = expf(-d2/(2.f*sc*sc + 1e-8f)) * mm;
            }
        }
        if (tid < 24) sW1e[tid >> 3][120 + (tid & 7)] = 0.f;
        team_bar(1);
        // D. W2 + mask ext
        for (int t = tid; t < 560; t += 320) {
            int a = t_ij[t], b2 = t_jk[t], c2 = t_ik[t];
            #pragma unroll
            for (int s = 0; s < 3; ++s) sW2e[s][t] = sW1e[s][a]*sW1e[s][b2]*sW1e[s][c2];
        }
        if (tid < 48) sW2e[tid >> 4][560 + (tid & 15)] = sMask[tid & 15];
        team_bar(2);
        // E. O build + rsA (wave roles)
        if (w < 3) {
            int s = w;
            f32x4 acc = {0.f, 0.f, 0.f, 0.f};
            __builtin_amdgcn_s_setprio(1);
            #pragma unroll 3
            for (int kt = 0; kt < 18; ++kt) {
                U4 ub; ub.u4 = ufrag[kt*64 + lane];
                const float4* w4 = (const float4*)&sW2e[s][kt*32 + kq*8];
                float4 wa = w4[0], wb = w4[1];
                U4 av;
                av.us[0] = f2bf(wa.x * bf2f(ub.us[0]));
                av.us[1] = f2bf(wa.y * bf2f(ub.us[1]));
                av.us[2] = f2bf(wa.z * bf2f(ub.us[2]));
                av.us[3] = f2bf(wa.w * bf2f(ub.us[3]));
                av.us[4] = f2bf(wb.x * bf2f(ub.us[4]));
                av.us[5] = f2bf(wb.y * bf2f(ub.us[5]));
                av.us[6] = f2bf(wb.z * bf2f(ub.us[6]));
                av.us[7] = f2bf(wb.w * bf2f(ub.us[7]));
                acc = __builtin_amdgcn_mfma_f32_16x16x32_bf16(av.bv, ub.bv, acc, 0, 0, 0);
            }
            __builtin_amdgcn_s_setprio(0);
            #pragma unroll
            for (int e = 0; e < 4; ++e) {
                int row = kq*4 + e;
                sO[(3+s)*256 + row*16 + rr] = acc[e] + TAUF*C1[row*16 + rr];
            }
        } else if (w == 3) {
            f32x4 acc3[3];
            acc3[0] = 0.f; acc3[1] = 0.f; acc3[2] = 0.f;
            __builtin_amdgcn_s_setprio(1);
            #pragma unroll
            for (int kt = 0; kt < 4; ++kt) {
                U4 ub; ub.u4 = b1frag[kt*64 + lane];
                float uf[8];
                #pragma unroll
                for (int j = 0; j < 8; ++j) uf[j] = bf2f(ub.us[j]);
                #pragma unroll
                for (int s = 0; s < 3; ++s) {
                    const float4* w4 = (const float4*)&sW1e[s][kt*32 + kq*8];
                    float4 wa = w4[0], wb = w4[1];
                    U4 av;
                    av.us[0] = f2bf(wa.x * uf[0]);
                    av.us[1] = f2bf(wa.y * uf[1]);
                    av.us[2] = f2bf(wa.z * uf[2]);
                    av.us[3] = f2bf(wa.w * uf[3]);
                    av.us[4] = f2bf(wb.x * uf[4]);
                    av.us[5] = f2bf(wb.y * uf[5]);
                    av.us[6] = f2bf(wb.z * uf[6]);
                    av.us[7] = f2bf(wb.w * uf[7]);
                    acc3[s] = __builtin_amdgcn_mfma_f32_16x16x32_bf16(av.bv, ub.bv, acc3[s], 0, 0, 0);
                }
            }
            __builtin_amdgcn_s_setprio(0);
            #pragma unroll
            for (int s = 0; s < 3; ++s)
                #pragma unroll
                for (int e = 0; e < 4; ++e) {
                    int row = kq*4 + e;
                    sO[s*256 + row*16 + rr] = acc3[s][e] + ((row == rr) ? TAUF : 0.f);
                }
        } else {
            f32x4 acc = {0.f, 0.f, 0.f, 0.f};
            int srow = (rr < 3) ? rr : 0;
            __builtin_amdgcn_s_setprio(1);
            #pragma unroll 3
            for (int kt = 0; kt < 18; ++kt) {
                U4 gb; gb.u4 = gfrag[kt*64 + lane];
                const float4* w4 = (const float4*)&sW2e[srow][kt*32 + kq*8];
                float4 wa = w4[0], wb = w4[1];
                U4 av;
                av.us[0] = f2bf(wa.x); av.us[1] = f2bf(wa.y);
                av.us[2] = f2bf(wa.z); av.us[3] = f2bf(wa.w);
                av.us[4] = f2bf(wb.x); av.us[5] = f2bf(wb.y);
                av.us[6] = f2bf(wb.z); av.us[7] = f2bf(wb.w);
                acc = __builtin_amdgcn_mfma_f32_16x16x32_bf16(av.bv, gb.bv, acc, 0, 0, 0);
            }
            __builtin_amdgcn_s_setprio(0);
            if (kq == 0) {
                #pragma unroll
                for (int e = 0; e < 3; ++e)
                    sRsA[e*16 + rr] = acc[e] + TAUF * r2[rr];
            }
        }
        team_bar(3);
        if (tid == 0)
            __hip_atomic_store(&sFlagO, 1, __ATOMIC_RELEASE, __HIP_MEMORY_SCOPE_WORKGROUP);

        // F (geo team's own col-tile 11+w): streaming accP (R14 form)
        {
            const int col = (11 + w)*16 + rr;
            float accP[16];
            #pragma unroll
            for (int k = 0; k < 16; ++k) accP[k] = 0.f;
            for (int blk = 0; blk < 6; ++blk) {
                f32x4 ya = {0.f, 0.f, 0.f, 0.f};
                #pragma unroll
                for (int half = 0; half < 2; ++half) {
                    U4 qf[4];
                    #pragma unroll
                    for (int kt = 0; kt < 4; ++kt)
                        qf[kt].u4 = *(const uint4*)(Qt + ((size_t)(blk*256 + (11+w)*16 + rr))*256 + (half*4 + kt)*32 + kq*8);
                    #pragma unroll
                    for (int kt = 0; kt < 4; ++kt) {
                        int kg = (half*4 + kt)*4 + kq;
                        int swz = (kg & 24) | ((kg & 7) ^ (rr & 7));
                        bf16x8 af = *(const bf16x8*)&sNB[rr*256 + swz*8];
                        ya = __builtin_amdgcn_mfma_f32_16x16x32_bf16(af, qf[kt].bv, ya, 0, 0, 0);
                    }
                }
                #pragma unroll
                for (int k = 0; k < 16; ++k) {
                    float4 ov = *(const float4*)&sO[blk*256 + k*16 + kq*4];
                    accP[k] += ov.x*ya[0] + ov.y*ya[1] + ov.z*ya[2] + ov.w*ya[3];
                }
            }
            #pragma unroll
            for (int k = 0; k < 16; ++k) {
                accP[k] += __shfl_xor(accP[k], 16);
                accP[k] += __shfl_xor(accP[k], 32);
            }
            float b0v = bias0[col], c0v = ce[col], c1v = ce[256+col], c2v = ce[512+col];
            #pragma unroll
            for (int e = 0; e < 4; ++e) {
                int k = kq*4 + e;
                float v = accP[k] + b0v
                        + sRsA[     k] * c0v
                        + sRsA[16 + k] * c1v
                        + sRsA[32 + k] * c2v
                        + x[((size_t)bb*16 + k)*256 + col];
                sFbuf[k][col] = v;
            }
        }
    } else {
        // ================== Y TEAM (waves 5-15): tile w-5, overlap with geometry ==================
        const int ty = w - 5;
        const int col = ty*16 + rr;
        f32x4 ya[6];
        #pragma unroll
        for (int blk = 0; blk < 6; ++blk) {
            ya[blk] = 0.f;
            #pragma unroll
            for (int half = 0; half < 2; ++half) {
                U4 qf[4];
                #pragma unroll
                for (int kt = 0; kt < 4; ++kt)
                    qf[kt].u4 = *(const uint4*)(Qt + ((size_t)(blk*256 + ty*16 + rr))*256 + (half*4 + kt)*32 + kq*8);
                #pragma unroll
                for (int kt = 0; kt < 4; ++kt) {
                    int kg = (half*4 + kt)*4 + kq;
                    int swz = (kg & 24) | ((kg & 7) ^ (rr & 7));
                    bf16x8 af = *(const bf16x8*)&sNB[rr*256 + swz*8];
                    ya[blk] = __builtin_amdgcn_mfma_f32_16x16x32_bf16(af, qf[kt].bv, ya[blk], 0, 0, 0);
                }
            }
        }
        // wait for O / rsA
        while (__hip_atomic_load(&sFlagO, __ATOMIC_ACQUIRE, __HIP_MEMORY_SCOPE_WORKGROUP) == 0)
            __builtin_amdgcn_s_sleep(1);
        float accP[16];
        #pragma unroll
        for (int k = 0; k < 16; ++k) accP[k] = 0.f;
        #pragma unroll
        for (int blk = 0; blk < 6; ++blk)
            #pragma unroll
            for (int k = 0; k < 16; ++k) {
                float4 ov = *(const float4*)&sO[blk*256 + k*16 + kq*4];
                accP[k] += ov.x*ya[blk][0] + ov.y*ya[blk][1] + ov.z*ya[blk][2] + ov.w*ya[blk][3];
            }
        #pragma unroll
        for (int k = 0; k < 16; ++k) {
            accP[k] += __shfl_xor(accP[k], 16);
            accP[k] += __shfl_xor(accP[k], 32);
        }
        float b0v = bias0[col], c0v = ce[col], c1v = ce[256+col], c2v = ce[512+col];
        #pragma unroll
        for (int e = 0; e < 4; ++e) {
            int k = kq*4 + e;
            float v = accP[k] + b0v
                    + sRsA[     k] * c0v
                    + sRsA[16 + k] * c1v
                    + sRsA[32 + k] * c2v
                    + x[((size_t)bb*16 + k)*256 + col];
            sFbuf[k][col] = v;
        }
    }
    __syncthreads();                                     // barrier #2

    // ---- G. LN2 -> sNB (x2n bf16 chunks) ----
    {
        const int r = w, q = lane;
        float v[4];
        v[0] = sFbuf[r][q*4+0]; v[1] = sFbuf[r][q*4+1];
        v[2] = sFbuf[r][q*4+2]; v[3] = sFbuf[r][q*4+3];
        float sum = v[0]+v[1]+v[2]+v[3];
        float ss  = v[0]*v[0]+v[1]*v[1]+v[2]*v[2]+v[3]*v[3];
        #pragma unroll
        for (int o = 32; o; o >>= 1) { sum += __shfl_xor(sum, o); ss += __shfl_xor(ss, o); }
        float mean = sum * (1.f/256.f);
        float rstd = rsqrtf(ss*(1.f/256.f) - mean*mean + LNEPS);
        ushort4 pk;
        pk.x = f2bf((v[0]-mean)*rstd*n2g[q*4+0] + n2b[q*4+0]);
        pk.y = f2bf((v[1]-mean)*rstd*n2g[q*4+1] + n2b[q*4+1]);
        pk.z = f2bf((v[2]-mean)*rstd*n2g[q*4+2] + n2b[q*4+2]);
        pk.w = f2bf((v[3]-mean)*rstd*n2g[q*4+3] + n2b[q*4+3]);
        int kg = q >> 1;
        int swz = (kg & 24) | ((kg & 7) ^ (r & 7));
        *(ushort4*)&sNB[r*256 + swz*8 + (q & 1)*4] = pk;
    }
    __syncthreads();                                     // barrier #3

    // ---- H. FFN1: wave w -> 4 n-tiles; h -> sH ----
    {
        U4 wb[8];
        #pragma unroll
        for (int kt = 0; kt < 8; ++kt)
            wb[kt].u4 = *(const uint4*)(w1t + (size_t)((w*4+0)*16 + rr)*256 + kt*32 + kq*8);
        #pragma unroll
        for (int j = 0; j < 4; ++j) {
            int nt = w*4 + j;
            f32x4 acc = {0.f, 0.f, 0.f, 0.f};
            __builtin_amdgcn_s_setprio(1);
            #pragma unroll
            for (int kt = 0; kt < 8; ++kt) {
                int kg = kt*4 + kq;
                int swz = (kg & 24) | ((kg & 7) ^ (rr & 7));
                bf16x8 af = *(const bf16x8*)&sNB[rr*256 + swz*8];
                acc = __builtin_amdgcn_mfma_f32_16x16x32_bf16(af, wb[kt].bv, acc, 0, 0, 0);
            }
            __builtin_amdgcn_s_setprio(0);
            if (j < 3) {
                #pragma unroll
                for (int kt = 0; kt < 8; ++kt)
                    wb[kt].u4 = *(const uint4*)(w1t + (size_t)((nt+1)*16 + rr)*256 + kt*32 + kq*8);
            }
            int n = nt*16 + rr;
            float bias = f1b[n];
            int hkg = n >> 3, hlo = n & 7;
            #pragma unroll
            for (int e = 0; e < 4; ++e) {
                int m = kq*4 + e;
                float v = acc[e] + bias;
                v = 0.5f * v * (1.f + erff(v * 0.70710678118654752f));
                int hswz = (hkg & 120) | ((hkg & 7) ^ (m & 7));
                sH[m*1024 + hswz*8 + hlo] = f2bf(v);
            }
        }
    }
    __syncthreads();                                     // barrier #4

    // ---- I. FFN2: wave w -> 1 n-tile; out = x2 + h @ w2t^T + b2 ----
    {
        U4 qb[8];
        #pragma unroll
        for (int kt = 0; kt < 8; ++kt)
            qb[kt].u4 = *(const uint4*)(w2t + (size_t)(w*16 + rr)*1024 + kt*32 + kq*8);
        f32x4 acc = {0.f, 0.f, 0.f, 0.f};
        #pragma unroll
        for (int grp = 0; grp < 4; ++grp) {
            __builtin_amdgcn_s_setprio(1);
            #pragma unroll
            for (int kt = 0; kt < 8; ++kt) {
                int hkg = (grp*8 + kt)*4 + kq;
                int hswz = (hkg & 120) | ((hkg & 7) ^ (rr & 7));
                bf16x8 af = *(const bf16x8*)&sH[rr*1024 + hswz*8];
                acc = __builtin_amdgcn_mfma_f32_16x16x32_bf16(af, qb[kt].bv, acc, 0, 0, 0);
            }
            __builtin_amdgcn_s_setprio(0);
            if (grp < 3) {
                #pragma unroll
                for (int kt = 0; kt < 8; ++kt)
                    qb[kt].u4 = *(const uint4*)(w2t + (size_t)(w*16 + rr)*1024 + ((grp+1)*8 + kt)*32 + kq*8);
            }
        }
        int col = w*16 + rr;
        float bias = f2b[col];
        #pragma unroll
        for (int e = 0; e < 4; ++e) {
            int row = kq*4 + e;
            outp[((size_t)bb*16 + row)*256 + col] = acc[e] + bias + sFbuf[row][col];
        }
    }
}

extern "C" void kernel_launch(void* const* d_in, const int* in_sizes, int n_in,
                              void* d_out, int out_size, void* d_ws, size_t ws_size,
                              hipStream_t stream)
{
    (void)in_sizes; (void)n_in; (void)out_size;
    const float* x      = (const float*)d_in[0];
    const float* mask   = (const float*)d_in[1];
    const float* B1g    = (const float*)d_in[2];
    const float* B2g    = (const float*)d_in[3];
    const float* absB1  = (const float*)d_in[4];
    const int*   e_i    = (const int*)d_in[5];
    const int*   e_j    = (const int*)d_in[6];
    const int*   t_ij   = (const int*)d_in[7];
    const int*   t_jk   = (const int*)d_in[8];
    const int*   t_ik   = (const int*)d_in[9];
    const float* geom_w = (const float*)d_in[10];
    const float* geom_b = (const float*)d_in[11];
    const float* log_sc = (const float*)d_in[12];
    const float* wv0_w  = (const float*)d_in[13];
    const float* wv0_b  = (const float*)d_in[14];
    const float* wein_w = (const float*)d_in[15];
    const float* wein_b = (const float*)d_in[16];
    const float* out_w  = (const float*)d_in[17];
    const float* out_b  = (const float*)d_in[18];
    const float* n1_g   = (const float*)d_in[19];
    const float* n1_b   = (const float*)d_in[20];
    const float* n2_g   = (const float*)d_in[21];
    const float* n2_b   = (const float*)d_in[22];
    const float* ffn1_w = (const float*)d_in[23];
    const float* ffn1_b = (const float*)d_in[24];
    const float* ffn2_w = (const float*)d_in[25];
    const float* ffn2_b = (const float*)d_in[26];

    float* out = (float*)d_out;
    float* ws  = (float*)d_ws;
    if (ws_size < (size_t)WS_FLOATS * sizeof(float)) return;

    float* ce    = ws + CE_OFF;
    float* bias0 = ws + B0_OFF;
    float* C1    = ws + C1_OFF;
    float* r2    = ws + R2_OFF;
    uint4* ufrag  = (uint4*)(ws + UF_OFF);
    uint4* b1frag = (uint4*)(ws + B1F_OFF);
    uint4* gfrag  = (uint4*)(ws + GF_OFF);
    unsigned short* Qt  = (unsigned short*)(ws + QT_OFF);
    unsigned short* w1t = (unsigned short*)(ws + W1T_OFF);
    unsigned short* w2t = (unsigned short*)(ws + W2T_OFF);

    prep_k<<<269, 256, 0, stream>>>(wv0_w, wein_w, out_w, ffn1_w, ffn2_w,
                                    wv0_b, wein_b, out_b, B1g, absB1, B2g,
                                    Qt, w1t, w2t,
                                    ce, bias0, C1, r2,
                                    ufrag, b1frag, gfrag);
    k_mega<<<256, 1024, 0, stream>>>(x, mask, e_i, e_j, t_ij, t_jk, t_ik,
                                     geom_w, geom_b, log_sc, n1_g, n1_b, n2_g, n2_b,
                                     C1, r2, ufrag, b1frag, gfrag,
                                     Qt, bias0, ce,
                                     w1t, ffn1_b, w2t, ffn2_b, out);
}

// Round 16
// 76.691 us; speedup vs baseline: 1.4923x; 1.1468x over previous
//
#include <hip/hip_runtime.h>
#include <math.h>

#define TAUF  1.0e-4f
#define LNEPS 1.0e-5f

typedef __bf16 bf16x8 __attribute__((ext_vector_type(8)));
typedef float  f32x4  __attribute__((ext_vector_type(4)));

union U4 { uint4 u4; unsigned short us[8]; bf16x8 bv; };

static __device__ __forceinline__ unsigned short f2bf(float f) {
    union { float f; unsigned u; } v; v.f = f;
    unsigned r = v.u + 0x7fffu + ((v.u >> 16) & 1u);
    return (unsigned short)(r >> 16);
}
static __device__ __forceinline__ float bf2f(unsigned short h) {
    union { unsigned u; float f; } v; v.u = ((unsigned)h) << 16;
    return v.f;
}

// ---------------- workspace layout (float offsets, all 16B-aligned) ----------------
static const unsigned CE_OFF   = 0u;         // 768
static const unsigned B0_OFF   = 768u;       // 256
static const unsigned C1_OFF   = 1024u;      // 256
static const unsigned R2_OFF   = 1280u;      // 16
static const unsigned UF_OFF   = 1296u;      // 18*64 uint4 = 4608 f
static const unsigned B1F_OFF  = 5904u;      // 4*64 uint4  = 1024 f
static const unsigned GF_OFF   = 6928u;      // 18*64 uint4 = 4608 f
static const unsigned QT_OFF   = 11536u;     // 393216 bf16 = 196608 f
static const unsigned W1T_OFF  = 208144u;    // 262144 bf16 = 131072 f
static const unsigned W2T_OFF  = 339216u;    // 262144 bf16 = 131072 f
static const unsigned WS_FLOATS = 470288u;   // ~1.9 MB

// ================= prep: consolidated (grid 269); bias fold de-staged =================
__launch_bounds__(256, 2)
__global__ void prep_k(const float* __restrict__ wv0_w, const float* __restrict__ wein_w,
                       const float* __restrict__ out_w,
                       const float* __restrict__ ffn1_w, const float* __restrict__ ffn2_w,
                       const float* __restrict__ wv0_b, const float* __restrict__ wein_b,
                       const float* __restrict__ out_b,
                       const float* __restrict__ B1g, const float* __restrict__ absB1,
                       const float* __restrict__ B2g,
                       unsigned short* __restrict__ Qt,
                       unsigned short* __restrict__ w1t, unsigned short* __restrict__ w2t,
                       float* __restrict__ ce, float* __restrict__ bias0,
                       float* __restrict__ C1, float* __restrict__ r2,
                       uint4* __restrict__ ufrag, uint4* __restrict__ b1frag,
                       uint4* __restrict__ gfrag)
{
    __shared__ float sPool[12800];
    int b = blockIdx.x, tid = threadIdx.x;
    if (b < 96) {
        float* sTf = sPool;                                     // [64][68] f32
        unsigned short* sBb = (unsigned short*)(sPool + 4352);  // [64][264] bf16
        int by = b >> 2, bx = b & 3;
        int row0 = by * 64, col0 = bx * 64;
        int z = row0 >> 8, o0 = row0 & 255;
        int s = (z < 3) ? z : z - 3;
        const float* Wsel = (z < 3) ? wv0_w : wein_w;
        int lane = tid & 63, w = tid >> 6;
        int rr = lane & 15, kq = lane >> 4;

        #pragma unroll
        for (int i = 0; i < 16; ++i) {
            int idx = i*256 + tid;
            int row = idx >> 6, c4 = idx & 63;
            float4 v = *(const float4*)(Wsel + (size_t)(col0 + row)*768 + s*256 + c4*4);
            ushort4 pk;
            pk.x = f2bf(v.x); pk.y = f2bf(v.y); pk.z = f2bf(v.z); pk.w = f2bf(v.w);
            *(ushort4*)&sBb[row*264 + c4*4] = pk;
        }
        __syncthreads();

        f32x4 acc[4];
        #pragma unroll
        for (int cg = 0; cg < 4; ++cg) acc[cg] = 0.f;
        for (int st = 0; st < 4; ++st) {
            #pragma unroll
            for (int i = 0; i < 4; ++i) {
                int idx = i*256 + tid;
                int dd = idx >> 4, q = idx & 15;
                float4 v = *(const float4*)(out_w + (size_t)(z*256 + st*64 + dd)*256 + o0 + q*4);
                *(float4*)&sTf[dd*68 + q*4] = v;
            }
            __syncthreads();
            #pragma unroll
            for (int ks2 = 0; ks2 < 2; ++ks2) {
                int ks = st*2 + ks2;
                U4 av;
                #pragma unroll
                for (int j = 0; j < 8; ++j)
                    av.us[j] = f2bf(sTf[(ks2*32 + kq*8 + j)*68 + w*16 + rr]);
                #pragma unroll
                for (int cg = 0; cg < 4; ++cg) {
                    bf16x8 bv = *(const bf16x8*)&sBb[(cg*16 + rr)*264 + ks*32 + kq*8];
                    acc[cg] = __builtin_amdgcn_mfma_f32_16x16x32_bf16(av.bv, bv, acc[cg], 0, 0, 0);
                }
            }
            __syncthreads();
        }
        #pragma unroll
        for (int cg = 0; cg < 4; ++cg)
            #pragma unroll
            for (int e = 0; e < 4; ++e) {
                int row = row0 + w*16 + kq*4 + e;
                int col = col0 + cg*16 + rr;
                Qt[(size_t)row*256 + col] = f2bf(acc[cg][e]);
            }
    } else if (b < 160) {
        float (*tile)[33] = (float(*)[33])sPool;
        int tx = tid & 31, ty = tid >> 5;
        for (int ti = 0; ti < 4; ++ti) {
            int bi = (b - 96)*4 + ti;
            int c0 = (bi & 31) * 32, r0 = (bi >> 5) * 32;
            if (ti) __syncthreads();
            #pragma unroll
            for (int i = 0; i < 4; ++i)
                tile[ty + i*8][tx] = ffn1_w[(size_t)(r0 + ty + i*8)*1024 + c0 + tx];
            __syncthreads();
            #pragma unroll
            for (int i = 0; i < 4; ++i)
                w1t[(size_t)(c0 + ty + i*8)*256 + r0 + tx] = f2bf(tile[tx][ty + i*8]);
        }
    } else if (b < 224) {
        float (*tile)[33] = (float(*)[33])sPool;
        int tx = tid & 31, ty = tid >> 5;
        for (int ti = 0; ti < 4; ++ti) {
            int bi = (b - 160)*4 + ti;
            int c0 = (bi & 7) * 32, r0 = (bi >> 3) * 32;
            if (ti) __syncthreads();
            #pragma unroll
            for (int i = 0; i < 4; ++i)
                tile[ty + i*8][tx] = ffn2_w[(size_t)(r0 + ty + i*8)*256 + c0 + tx];
            __syncthreads();
            #pragma unroll
            for (int i = 0; i < 4; ++i)
                w2t[(size_t)(c0 + ty + i*8)*1024 + r0 + tx] = f2bf(tile[tx][ty + i*8]);
        }
    } else if (b < 228) {
        // ---- bias folds: direct pipelined accumulation (no LDS staging, no barriers) ----
        int which = b - 224;
        int o = tid;
        float a0 = 0.f, a1 = 0.f, a2 = 0.f, a3 = 0.f;
        if (which == 3) {
            const float* p = out_w + o;
            for (int r = 0; r < 768; r += 8) {
                a0 += wv0_b[r+0] * p[(size_t)(r+0)*256];
                a1 += wv0_b[r+1] * p[(size_t)(r+1)*256];
                a2 += wv0_b[r+2] * p[(size_t)(r+2)*256];
                a3 += wv0_b[r+3] * p[(size_t)(r+3)*256];
                a0 += wv0_b[r+4] * p[(size_t)(r+4)*256];
                a1 += wv0_b[r+5] * p[(size_t)(r+5)*256];
                a2 += wv0_b[r+6] * p[(size_t)(r+6)*256];
                a3 += wv0_b[r+7] * p[(size_t)(r+7)*256];
            }
            bias0[o] = out_b[o] + TAUF * ((a0+a1) + (a2+a3));
        } else {
            const float* p = out_w + (size_t)(768 + which*256)*256 + o;
            const float* wb = wein_b + which*256;
            for (int r = 0; r < 256; r += 8) {
                a0 += wb[r+0] * p[(size_t)(r+0)*256];
                a1 += wb[r+1] * p[(size_t)(r+1)*256];
                a2 += wb[r+2] * p[(size_t)(r+2)*256];
                a3 += wb[r+3] * p[(size_t)(r+3)*256];
                a0 += wb[r+4] * p[(size_t)(r+4)*256];
                a1 += wb[r+5] * p[(size_t)(r+5)*256];
                a2 += wb[r+6] * p[(size_t)(r+6)*256];
                a3 += wb[r+7] * p[(size_t)(r+7)*256];
            }
            ce[which*256 + o] = (a0+a1) + (a2+a3);
        }
    } else if (b == 228) {
        int p = tid >> 4, q = tid & 15;
        float c1 = 0.f;
        for (int e = 0; e < 120; ++e) c1 += absB1[p*120+e] * absB1[q*120+e];
        C1[tid] = c1;
        if (tid < 16) {
            float bb = 0.f;
            for (int e = 0; e < 120; ++e) bb += absB1[tid*120+e];
            r2[tid] = bb;
        }
    } else if (b < 247) {
        unsigned short (*sFrag)[8] = (unsigned short(*)[8])sPool;
        int kt = b - 229;
        #pragma unroll
        for (int it = 0; it < 2; ++it) {
            int item = it*256 + tid;
            int lane = item >> 3, j = item & 7;
            int col = lane & 15, kq = lane >> 4;
            int t = kt*32 + kq*8 + j;
            float v = 0.f;
            if (t < 560) {
                for (int e = 0; e < 120; ++e) v += absB1[col*120+e] * B2g[e*560+t];
            } else {
                int p = t - 560;
                for (int e = 0; e < 120; ++e) v += absB1[col*120+e] * B1g[p*120+e];
            }
            sFrag[lane][j] = f2bf(v);
        }
        __syncthreads();
        if (tid < 64) {
            U4 o;
            #pragma unroll
            for (int j = 0; j < 8; ++j) o.us[j] = sFrag[tid][j];
            ufrag[kt*64 + tid] = o.u4;
        }
    } else if (b < 251) {
        if (tid < 64) {
            int lane = tid, col = lane & 15, kq = lane >> 4;
            int kt = b - 247;
            U4 o;
            #pragma unroll
            for (int j = 0; j < 8; ++j) {
                int e = kt*32 + kq*8 + j;
                o.us[j] = f2bf((e < 120) ? B1g[col*120 + e] : 0.f);
            }
            b1frag[kt*64 + lane] = o.u4;
        }
    } else {
        unsigned short (*sFrag)[8] = (unsigned short(*)[8])sPool;
        int kt = b - 251;
        #pragma unroll
        for (int it = 0; it < 2; ++it) {
            int item = it*256 + tid;
            int lane = item >> 3, j = item & 7;
            int col = lane & 15, kq = lane >> 4;
            int t = kt*32 + kq*8 + j;
            float g;
            if (t < 560) {
                float u = 0.f, sgv = 0.f;
                for (int e = 0; e < 120; ++e) {
                    float bv = B2g[e*560+t];
                    u += absB1[col*120+e] * bv;
                    sgv += bv;
                }
                g = sgv * u;
            } else {
                int p = t - 560;
                float c0 = 0.f, r1v = 0.f;
                for (int e = 0; e < 120; ++e) {
                    float bv = B1g[p*120+e];
                    c0 += absB1[col*120+e] * bv;
                    r1v += bv;
                }
                g = c0 * r1v;
            }
            sFrag[lane][j] = f2bf(g);
        }
        __syncthreads();
        if (tid < 64) {
            U4 o;
            #pragma unroll
            for (int j = 0; j < 8; ++j) o.us[j] = sFrag[tid][j];
            gfrag[kt*64 + tid] = o.u4;
        }
    }
}

// ============== k_mega: R15 async wave-team structure + cheap gelu ==============
__launch_bounds__(1024, 4)
__global__ void k_mega(const float* __restrict__ x, const float* __restrict__ mask,
                       const int* __restrict__ e_i, const int* __restrict__ e_j,
                       const int* __restrict__ t_ij, const int* __restrict__ t_jk,
                       const int* __restrict__ t_ik,
                       const float* __restrict__ geom_w, const float* __restrict__ geom_b,
                       const float* __restrict__ log_sc,
                       const float* __restrict__ n1_g, const float* __restrict__ n1_b,
                       const float* __restrict__ n2g, const float* __restrict__ n2b,
                       const float* __restrict__ C1, const float* __restrict__ r2,
                       const uint4* __restrict__ ufrag, const uint4* __restrict__ b1frag,
                       const uint4* __restrict__ gfrag,
                       const unsigned short* __restrict__ Qt,
                       const float* __restrict__ bias0, const float* __restrict__ ce,
                       const unsigned short* __restrict__ w1t, const float* __restrict__ f1b,
                       const unsigned short* __restrict__ w2t, const float* __restrict__ f2b,
                       float* __restrict__ outp)
{
    __shared__ float sFbuf[16][264];           // xn (A..B), then x2 (F..I)
    __shared__ unsigned short sNB[16*256];     // bf16 xn chunks (A..F), then x2n (G,H)
    __shared__ unsigned short sH[16*1024];     // h, frag layout
    __shared__ float sP[16][17];
    __shared__ float sW1e[3][128];
    __shared__ float sW2e[3][576];
    __shared__ float sMask[16];
    __shared__ float sO[6*256];
    __shared__ float sRsA[48];
    __shared__ int sCnt[4];
    __shared__ int sFlagO;

    const int bb = blockIdx.x, tid = threadIdx.x;
    const int w = tid >> 6, lane = tid & 63;
    const int rr = lane & 15, kq = lane >> 4;

    // ---- A. LayerNorm 1 (all waves) + flag init ----
    {
        if (tid < 4) sCnt[tid] = 0;
        if (tid == 4) sFlagO = 0;
        const int r = w, q = lane;
        const float* row = x + ((size_t)bb*16 + r)*256 + q*4;
        float4 va = *(const float4*)row;
        float v[4] = {va.x, va.y, va.z, va.w};
        float sum = v[0]+v[1]+v[2]+v[3];
        float ss  = v[0]*v[0]+v[1]*v[1]+v[2]*v[2]+v[3]*v[3];
        #pragma unroll
        for (int o = 32; o; o >>= 1) { sum += __shfl_xor(sum, o); ss += __shfl_xor(ss, o); }
        float mean = sum * (1.f/256.f);
        float rstd = rsqrtf(ss*(1.f/256.f) - mean*mean + LNEPS);
        ushort4 pk;
        float xv0 = (v[0]-mean)*rstd*n1_g[q*4+0] + n1_b[q*4+0];
        float xv1 = (v[1]-mean)*rstd*n1_g[q*4+1] + n1_b[q*4+1];
        float xv2 = (v[2]-mean)*rstd*n1_g[q*4+2] + n1_b[q*4+2];
        float xv3 = (v[3]-mean)*rstd*n1_g[q*4+3] + n1_b[q*4+3];
        sFbuf[r][q*4+0] = xv0; sFbuf[r][q*4+1] = xv1;
        sFbuf[r][q*4+2] = xv2; sFbuf[r][q*4+3] = xv3;
        pk.x = f2bf(xv0); pk.y = f2bf(xv1); pk.z = f2bf(xv2); pk.w = f2bf(xv3);
        int kg = q >> 1;
        int swz = (kg & 24) | ((kg & 7) ^ (r & 7));
        *(ushort4*)&sNB[r*256 + swz*8 + (q & 1)*4] = pk;
        if (tid < 16) sMask[tid] = mask[bb*16 + tid];
    }
    __syncthreads();                                     // barrier #1

    auto team_bar = [&](int idx) {
        if ((tid & 63) == 0)
            __hip_atomic_fetch_add(&sCnt[idx], 1, __ATOMIC_ACQ_REL, __HIP_MEMORY_SCOPE_WORKGROUP);
        while (__hip_atomic_load(&sCnt[idx], __ATOMIC_ACQUIRE, __HIP_MEMORY_SCOPE_WORKGROUP) < 5)
            __builtin_amdgcn_s_sleep(1);
    };

    if (w < 5) {
        // ================== GEO TEAM (waves 0-4) ==================
        if (tid < 256) {
            int r = tid >> 4, g = tid & 15;
            float a0 = 0.f, a1 = 0.f, a2 = 0.f, a3 = 0.f;
            for (int c = 0; c < 256; c += 4) {
                float4 xv = *(const float4*)&sFbuf[r][c];
                a0 += xv.x * geom_w[(c+0)*16 + g];
                a1 += xv.y * geom_w[(c+1)*16 + g];
                a2 += xv.z * geom_w[(c+2)*16 + g];
                a3 += xv.w * geom_w[(c+3)*16 + g];
            }
            sP[r][g] = (a0+a1) + (a2+a3) + geom_b[g];
        }
        team_bar(0);
        if (tid < 120) {
            int e = tid, i0 = e_i[e], j0 = e_j[e];
            float d2 = 0.f;
            #pragma unroll
            for (int m = 0; m < 16; ++m) { float dd = sP[i0][m] - sP[j0][m]; d2 += dd*dd; }
            float mm = sMask[i0]*sMask[j0];
            d2 *= mm*mm;
            #pragma unroll
            for (int s = 0; s < 3; ++s) {
                float sc = __expf(log_sc[s]);
                sW1e[s][e] = __expf(-d2/(2.f*sc*sc + 1e-8f)) * mm;
            }
        }
        if (tid < 24) sW1e[tid >> 3][120 + (tid & 7)] = 0.f;
        team_bar(1);
        for (int t = tid; t < 560; t += 320) {
            int a = t_ij[t], b2 = t_jk[t], c2 = t_ik[t];
            #pragma unroll
            for (int s = 0; s < 3; ++s) sW2e[s][t] = sW1e[s][a]*sW1e[s][b2]*sW1e[s][c2];
        }
        if (tid < 48) sW2e[tid >> 4][560 + (tid & 15)] = sMask[tid & 15];
        team_bar(2);
        if (w < 3) {
            int s = w;
            f32x4 acc = {0.f, 0.f, 0.f, 0.f};
            __builtin_amdgcn_s_setprio(1);
            #pragma unroll 3
            for (int kt = 0; kt < 18; ++kt) {
                U4 ub; ub.u4 = ufrag[kt*64 + lane];
                const float4* w4 = (const float4*)&sW2e[s][kt*32 + kq*8];
                float4 wa = w4[0], wb = w4[1];
                U4 av;
                av.us[0] = f2bf(wa.x * bf2f(ub.us[0]));
                av.us[1] = f2bf(wa.y * bf2f(ub.us[1]));
                av.us[2] = f2bf(wa.z * bf2f(ub.us[2]));
                av.us[3] = f2bf(wa.w * bf2f(ub.us[3]));
                av.us[4] = f2bf(wb.x * bf2f(ub.us[4]));
                av.us[5] = f2bf(wb.y * bf2f(ub.us[5]));
                av.us[6] = f2bf(wb.z * bf2f(ub.us[6]));
                av.us[7] = f2bf(wb.w * bf2f(ub.us[7]));
                acc = __builtin_amdgcn_mfma_f32_16x16x32_bf16(av.bv, ub.bv, acc, 0, 0, 0);
            }
            __builtin_amdgcn_s_setprio(0);
            #pragma unroll
            for (int e = 0; e < 4; ++e) {
                int row = kq*4 + e;
                sO[(3+s)*256 + row*16 + rr] = acc[e] + TAUF*C1[row*16 + rr];
            }
        } else if (w == 3) {
            f32x4 acc3[3];
            acc3[0] = 0.f; acc3[1] = 0.f; acc3[2] = 0.f;
            __builtin_amdgcn_s_setprio(1);
            #pragma unroll
            for (int kt = 0; kt < 4; ++kt) {
                U4 ub; ub.u4 = b1frag[kt*64 + lane];
                float uf[8];
                #pragma unroll
                for (int j = 0; j < 8; ++j) uf[j] = bf2f(ub.us[j]);
                #pragma unroll
                for (int s = 0; s < 3; ++s) {
                    const float4* w4 = (const float4*)&sW1e[s][kt*32 + kq*8];
                    float4 wa = w4[0], wb = w4[1];
                    U4 av;
                    av.us[0] = f2bf(wa.x * uf[0]);
                    av.us[1] = f2bf(wa.y * uf[1]);
                    av.us[2] = f2bf(wa.z * uf[2]);
                    av.us[3] = f2bf(wa.w * uf[3]);
                    av.us[4] = f2bf(wb.x * uf[4]);
                    av.us[5] = f2bf(wb.y * uf[5]);
                    av.us[6] = f2bf(wb.z * uf[6]);
                    av.us[7] = f2bf(wb.w * uf[7]);
                    acc3[s] = __builtin_amdgcn_mfma_f32_16x16x32_bf16(av.bv, ub.bv, acc3[s], 0, 0, 0);
                }
            }
            __builtin_amdgcn_s_setprio(0);
            #pragma unroll
            for (int s = 0; s < 3; ++s)
                #pragma unroll
                for (int e = 0; e < 4; ++e) {
                    int row = kq*4 + e;
                    sO[s*256 + row*16 + rr] = acc3[s][e] + ((row == rr) ? TAUF : 0.f);
                }
        } else {
            f32x4 acc = {0.f, 0.f, 0.f, 0.f};
            int srow = (rr < 3) ? rr : 0;
            __builtin_amdgcn_s_setprio(1);
            #pragma unroll 3
            for (int kt = 0; kt < 18; ++kt) {
                U4 gb; gb.u4 = gfrag[kt*64 + lane];
                const float4* w4 = (const float4*)&sW2e[srow][kt*32 + kq*8];
                float4 wa = w4[0], wb = w4[1];
                U4 av;
                av.us[0] = f2bf(wa.x); av.us[1] = f2bf(wa.y);
                av.us[2] = f2bf(wa.z); av.us[3] = f2bf(wa.w);
                av.us[4] = f2bf(wb.x); av.us[5] = f2bf(wb.y);
                av.us[6] = f2bf(wb.z); av.us[7] = f2bf(wb.w);
                acc = __builtin_amdgcn_mfma_f32_16x16x32_bf16(av.bv, gb.bv, acc, 0, 0, 0);
            }
            __builtin_amdgcn_s_setprio(0);
            if (kq == 0) {
                #pragma unroll
                for (int e = 0; e < 3; ++e)
                    sRsA[e*16 + rr] = acc[e] + TAUF * r2[rr];
            }
        }
        team_bar(3);
        if (tid == 0)
            __hip_atomic_store(&sFlagO, 1, __ATOMIC_RELEASE, __HIP_MEMORY_SCOPE_WORKGROUP);

        // F (geo team's own col-tile 11+w)
        {
            const int col = (11 + w)*16 + rr;
            float accP[16];
            #pragma unroll
            for (int k = 0; k < 16; ++k) accP[k] = 0.f;
            for (int blk = 0; blk < 6; ++blk) {
                f32x4 ya = {0.f, 0.f, 0.f, 0.f};
                #pragma unroll
                for (int half = 0; half < 2; ++half) {
                    U4 qf[4];
                    #pragma unroll
                    for (int kt = 0; kt < 4; ++kt)
                        qf[kt].u4 = *(const uint4*)(Qt + ((size_t)(blk*256 + (11+w)*16 + rr))*256 + (half*4 + kt)*32 + kq*8);
                    #pragma unroll
                    for (int kt = 0; kt < 4; ++kt) {
                        int kg = (half*4 + kt)*4 + kq;
                        int swz = (kg & 24) | ((kg & 7) ^ (rr & 7));
                        bf16x8 af = *(const bf16x8*)&sNB[rr*256 + swz*8];
                        ya = __builtin_amdgcn_mfma_f32_16x16x32_bf16(af, qf[kt].bv, ya, 0, 0, 0);
                    }
                }
                #pragma unroll
                for (int k = 0; k < 16; ++k) {
                    float4 ov = *(const float4*)&sO[blk*256 + k*16 + kq*4];
                    accP[k] += ov.x*ya[0] + ov.y*ya[1] + ov.z*ya[2] + ov.w*ya[3];
                }
            }
            #pragma unroll
            for (int k = 0; k < 16; ++k) {
                accP[k] += __shfl_xor(accP[k], 16);
                accP[k] += __shfl_xor(accP[k], 32);
            }
            float b0v = bias0[col], c0v = ce[col], c1v = ce[256+col], c2v = ce[512+col];
            #pragma unroll
            for (int e = 0; e < 4; ++e) {
                int k = kq*4 + e;
                float v = accP[k] + b0v
                        + sRsA[     k] * c0v
                        + sRsA[16 + k] * c1v
                        + sRsA[32 + k] * c2v
                        + x[((size_t)bb*16 + k)*256 + col];
                sFbuf[k][col] = v;
            }
        }
    } else {
        // ================== Y TEAM (waves 5-15): tile w-5, overlaps with geometry ==================
        const int ty = w - 5;
        const int col = ty*16 + rr;
        f32x4 ya[6];
        #pragma unroll
        for (int blk = 0; blk < 6; ++blk) {
            ya[blk] = 0.f;
            #pragma unroll
            for (int half = 0; half < 2; ++half) {
                U4 qf[4];
                #pragma unroll
                for (int kt = 0; kt < 4; ++kt)
                    qf[kt].u4 = *(const uint4*)(Qt + ((size_t)(blk*256 + ty*16 + rr))*256 + (half*4 + kt)*32 + kq*8);
                #pragma unroll
                for (int kt = 0; kt < 4; ++kt) {
                    int kg = (half*4 + kt)*4 + kq;
                    int swz = (kg & 24) | ((kg & 7) ^ (rr & 7));
                    bf16x8 af = *(const bf16x8*)&sNB[rr*256 + swz*8];
                    ya[blk] = __builtin_amdgcn_mfma_f32_16x16x32_bf16(af, qf[kt].bv, ya[blk], 0, 0, 0);
                }
            }
        }
        while (__hip_atomic_load(&sFlagO, __ATOMIC_ACQUIRE, __HIP_MEMORY_SCOPE_WORKGROUP) == 0)
            __builtin_amdgcn_s_sleep(1);
        float accP[16];
        #pragma unroll
        for (int k = 0; k < 16; ++k) accP[k] = 0.f;
        #pragma unroll
        for (int blk = 0; blk < 6; ++blk)
            #pragma unroll
            for (int k = 0; k < 16; ++k) {
                float4 ov = *(const float4*)&sO[blk*256 + k*16 + kq*4];
                accP[k] += ov.x*ya[blk][0] + ov.y*ya[blk][1] + ov.z*ya[blk][2] + ov.w*ya[blk][3];
            }
        #pragma unroll
        for (int k = 0; k < 16; ++k) {
            accP[k] += __shfl_xor(accP[k], 16);
            accP[k] += __shfl_xor(accP[k], 32);
        }
        float b0v = bias0[col], c0v = ce[col], c1v = ce[256+col], c2v = ce[512+col];
        #pragma unroll
        for (int e = 0; e < 4; ++e) {
            int k = kq*4 + e;
            float v = accP[k] + b0v
                    + sRsA[     k] * c0v
                    + sRsA[16 + k] * c1v
                    + sRsA[32 + k] * c2v
                    + x[((size_t)bb*16 + k)*256 + col];
            sFbuf[k][col] = v;
        }
    }
    __syncthreads();                                     // barrier #2

    // ---- G. LN2 -> sNB (x2n bf16 chunks) ----
    {
        const int r = w, q = lane;
        float v[4];
        v[0] = sFbuf[r][q*4+0]; v[1] = sFbuf[r][q*4+1];
        v[2] = sFbuf[r][q*4+2]; v[3] = sFbuf[r][q*4+3];
        float sum = v[0]+v[1]+v[2]+v[3];
        float ss  = v[0]*v[0]+v[1]*v[1]+v[2]*v[2]+v[3]*v[3];
        #pragma unroll
        for (int o = 32; o; o >>= 1) { sum += __shfl_xor(sum, o); ss += __shfl_xor(ss, o); }
        float mean = sum * (1.f/256.f);
        float rstd = rsqrtf(ss*(1.f/256.f) - mean*mean + LNEPS);
        ushort4 pk;
        pk.x = f2bf((v[0]-mean)*rstd*n2g[q*4+0] + n2b[q*4+0]);
        pk.y = f2bf((v[1]-mean)*rstd*n2g[q*4+1] + n2b[q*4+1]);
        pk.z = f2bf((v[2]-mean)*rstd*n2g[q*4+2] + n2b[q*4+2]);
        pk.w = f2bf((v[3]-mean)*rstd*n2g[q*4+3] + n2b[q*4+3]);
        int kg = q >> 1;
        int swz = (kg & 24) | ((kg & 7) ^ (r & 7));
        *(ushort4*)&sNB[r*256 + swz*8 + (q & 1)*4] = pk;
    }
    __syncthreads();                                     // barrier #3

    // ---- H. FFN1: wave w -> 4 n-tiles; h -> sH (cheap gelu) ----
    {
        U4 wb[8];
        #pragma unroll
        for (int kt = 0; kt < 8; ++kt)
            wb[kt].u4 = *(const uint4*)(w1t + (size_t)((w*4+0)*16 + rr)*256 + kt*32 + kq*8);
        #pragma unroll
        for (int j = 0; j < 4; ++j) {
            int nt = w*4 + j;
            f32x4 acc = {0.f, 0.f, 0.f, 0.f};
            __builtin_amdgcn_s_setprio(1);
            #pragma unroll
            for (int kt = 0; kt < 8; ++kt) {
                int kg = kt*4 + kq;
                int swz = (kg & 24) | ((kg & 7) ^ (rr & 7));
                bf16x8 af = *(const bf16x8*)&sNB[rr*256 + swz*8];
                acc = __builtin_amdgcn_mfma_f32_16x16x32_bf16(af, wb[kt].bv, acc, 0, 0, 0);
            }
            __builtin_amdgcn_s_setprio(0);
            if (j < 3) {
                #pragma unroll
                for (int kt = 0; kt < 8; ++kt)
                    wb[kt].u4 = *(const uint4*)(w1t + (size_t)((nt+1)*16 + rr)*256 + kt*32 + kq*8);
            }
            int n = nt*16 + rr;
            float bias = f1b[n];
            int hkg = n >> 3, hlo = n & 7;
            #pragma unroll
            for (int e = 0; e < 4; ++e) {
                int m = kq*4 + e;
                float v = acc[e] + bias;
                v = v / (1.f + __expf(-1.702f * v));          // gelu ~ v*sigmoid(1.702v)
                int hswz = (hkg & 120) | ((hkg & 7) ^ (m & 7));
                sH[m*1024 + hswz*8 + hlo] = f2bf(v);
            }
        }
    }
    __syncthreads();                                     // barrier #4

    // ---- I. FFN2: wave w -> 1 n-tile; out = x2 + h @ w2t^T + b2 ----
    {
        U4 qb[8];
        #pragma unroll
        for (int kt = 0; kt < 8; ++kt)
            qb[kt].u4 = *(const uint4*)(w2t + (size_t)(w*16 + rr)*1024 + kt*32 + kq*8);
        f32x4 acc = {0.f, 0.f, 0.f, 0.f};
        #pragma unroll
        for (int grp = 0; grp < 4; ++grp) {
            __builtin_amdgcn_s_setprio(1);
            #pragma unroll
            for (int kt = 0; kt < 8; ++kt) {
                int hkg = (grp*8 + kt)*4 + kq;
                int hswz = (hkg & 120) | ((hkg & 7) ^ (rr & 7));
                bf16x8 af = *(const bf16x8*)&sH[rr*1024 + hswz*8];
                acc = __builtin_amdgcn_mfma_f32_16x16x32_bf16(af, qb[kt].bv, acc, 0, 0, 0);
            }
            __builtin_amdgcn_s_setprio(0);
            if (grp < 3) {
                #pragma unroll
                for (int kt = 0; kt < 8; ++kt)
                    qb[kt].u4 = *(const uint4*)(w2t + (size_t)(w*16 + rr)*1024 + ((grp+1)*8 + kt)*32 + kq*8);
            }
        }
        int col = w*16 + rr;
        float bias = f2b[col];
        #pragma unroll
        for (int e = 0; e < 4; ++e) {
            int row = kq*4 + e;
            outp[((size_t)bb*16 + row)*256 + col] = acc[e] + bias + sFbuf[row][col];
        }
    }
}

extern "C" void kernel_launch(void* const* d_in, const int* in_sizes, int n_in,
                              void* d_out, int out_size, void* d_ws, size_t ws_size,
                              hipStream_t stream)
{
    (void)in_sizes; (void)n_in; (void)out_size;
    const float* x      = (const float*)d_in[0];
    const float* mask   = (const float*)d_in[1];
    const float* B1g    = (const float*)d_in[2];
    const float* B2g    = (const float*)d_in[3];
    const float* absB1  = (const float*)d_in[4];
    const int*   e_i    = (const int*)d_in[5];
    const int*   e_j    = (const int*)d_in[6];
    const int*   t_ij   = (const int*)d_in[7];
    const int*   t_jk   = (const int*)d_in[8];
    const int*   t_ik   = (const int*)d_in[9];
    const float* geom_w = (const float*)d_in[10];
    const float* geom_b = (const float*)d_in[11];
    const float* log_sc = (const float*)d_in[12];
    const float* wv0_w  = (const float*)d_in[13];
    const float* wv0_b  = (const float*)d_in[14];
    const float* wein_w = (const float*)d_in[15];
    const float* wein_b = (const float*)d_in[16];
    const float* out_w  = (const float*)d_in[17];
    const float* out_b  = (const float*)d_in[18];
    const float* n1_g   = (const float*)d_in[19];
    const float* n1_b   = (const float*)d_in[20];
    const float* n2_g   = (const float*)d_in[21];
    const float* n2_b   = (const float*)d_in[22];
    const float* ffn1_w = (const float*)d_in[23];
    const float* ffn1_b = (const float*)d_in[24];
    const float* ffn2_w = (const float*)d_in[25];
    const float* ffn2_b = (const float*)d_in[26];

    float* out = (float*)d_out;
    float* ws  = (float*)d_ws;
    if (ws_size < (size_t)WS_FLOATS * sizeof(float)) return;

    float* ce    = ws + CE_OFF;
    float* bias0 = ws + B0_OFF;
    float* C1    = ws + C1_OFF;
    float* r2    = ws + R2_OFF;
    uint4* ufrag  = (uint4*)(ws + UF_OFF);
    uint4* b1frag = (uint4*)(ws + B1F_OFF);
    uint4* gfrag  = (uint4*)(ws + GF_OFF);
    unsigned short* Qt  = (unsigned short*)(ws + QT_OFF);
    unsigned short* w1t = (unsigned short*)(ws + W1T_OFF);
    unsigned short* w2t = (unsigned short*)(ws + W2T_OFF);

    prep_k<<<269, 256, 0, stream>>>(wv0_w, wein_w, out_w, ffn1_w, ffn2_w,
                                    wv0_b, wein_b, out_b, B1g, absB1, B2g,
                                    Qt, w1t, w2t,
                                    ce, bias0, C1, r2,
                                    ufrag, b1frag, gfrag);
    k_mega<<<256, 1024, 0, stream>>>(x, mask, e_i, e_j, t_ij, t_jk, t_ik,
                                     geom_w, geom_b, log_sc, n1_g, n1_b, n2_g, n2_b,
                                     C1, r2, ufrag, b1frag, gfrag,
                                     Qt, bias0, ce,
                                     w1t, ffn1_b, w2t, ffn2_b, out);
}

// Round 17
// 76.005 us; speedup vs baseline: 1.5058x; 1.0090x over previous
//
#include <hip/hip_runtime.h>
#include <math.h>

#define TAUF  1.0e-4f
#define LNEPS 1.0e-5f

typedef __bf16 bf16x8 __attribute__((ext_vector_type(8)));
typedef float  f32x4  __attribute__((ext_vector_type(4)));

union U4 { uint4 u4; unsigned short us[8]; bf16x8 bv; };

static __device__ __forceinline__ unsigned short f2bf(float f) {
    union { float f; unsigned u; } v; v.f = f;
    unsigned r = v.u + 0x7fffu + ((v.u >> 16) & 1u);
    return (unsigned short)(r >> 16);
}
static __device__ __forceinline__ float bf2f(unsigned short h) {
    union { unsigned u; float f; } v; v.u = ((unsigned)h) << 16;
    return v.f;
}

// ---------------- workspace layout (float offsets, all 16B-aligned) ----------------
static const unsigned CE_OFF   = 0u;         // 768
static const unsigned B0_OFF   = 768u;       // 256
static const unsigned C1_OFF   = 1024u;      // 256
static const unsigned R2_OFF   = 1280u;      // 16
static const unsigned UF_OFF   = 1296u;      // 18*64 uint4 = 4608 f
static const unsigned B1F_OFF  = 5904u;      // 4*64 uint4  = 1024 f
static const unsigned GF_OFF   = 6928u;      // 18*64 uint4 = 4608 f
static const unsigned QT_OFF   = 11536u;     // 393216 bf16 = 196608 f
static const unsigned W1T_OFF  = 208144u;    // 262144 bf16 = 131072 f
static const unsigned W2T_OFF  = 339216u;    // 262144 bf16 = 131072 f
static const unsigned WS_FLOATS = 470288u;   // ~1.9 MB

// ================= prep: consolidated (grid 269); unchanged from R16 =================
__launch_bounds__(256, 2)
__global__ void prep_k(const float* __restrict__ wv0_w, const float* __restrict__ wein_w,
                       const float* __restrict__ out_w,
                       const float* __restrict__ ffn1_w, const float* __restrict__ ffn2_w,
                       const float* __restrict__ wv0_b, const float* __restrict__ wein_b,
                       const float* __restrict__ out_b,
                       const float* __restrict__ B1g, const float* __restrict__ absB1,
                       const float* __restrict__ B2g,
                       unsigned short* __restrict__ Qt,
                       unsigned short* __restrict__ w1t, unsigned short* __restrict__ w2t,
                       float* __restrict__ ce, float* __restrict__ bias0,
                       float* __restrict__ C1, float* __restrict__ r2,
                       uint4* __restrict__ ufrag, uint4* __restrict__ b1frag,
                       uint4* __restrict__ gfrag)
{
    __shared__ float sPool[12800];
    int b = blockIdx.x, tid = threadIdx.x;
    if (b < 96) {
        float* sTf = sPool;                                     // [64][68] f32
        unsigned short* sBb = (unsigned short*)(sPool + 4352);  // [64][264] bf16
        int by = b >> 2, bx = b & 3;
        int row0 = by * 64, col0 = bx * 64;
        int z = row0 >> 8, o0 = row0 & 255;
        int s = (z < 3) ? z : z - 3;
        const float* Wsel = (z < 3) ? wv0_w : wein_w;
        int lane = tid & 63, w = tid >> 6;
        int rr = lane & 15, kq = lane >> 4;

        #pragma unroll
        for (int i = 0; i < 16; ++i) {
            int idx = i*256 + tid;
            int row = idx >> 6, c4 = idx & 63;
            float4 v = *(const float4*)(Wsel + (size_t)(col0 + row)*768 + s*256 + c4*4);
            ushort4 pk;
            pk.x = f2bf(v.x); pk.y = f2bf(v.y); pk.z = f2bf(v.z); pk.w = f2bf(v.w);
            *(ushort4*)&sBb[row*264 + c4*4] = pk;
        }
        __syncthreads();

        f32x4 acc[4];
        #pragma unroll
        for (int cg = 0; cg < 4; ++cg) acc[cg] = 0.f;
        for (int st = 0; st < 4; ++st) {
            #pragma unroll
            for (int i = 0; i < 4; ++i) {
                int idx = i*256 + tid;
                int dd = idx >> 4, q = idx & 15;
                float4 v = *(const float4*)(out_w + (size_t)(z*256 + st*64 + dd)*256 + o0 + q*4);
                *(float4*)&sTf[dd*68 + q*4] = v;
            }
            __syncthreads();
            #pragma unroll
            for (int ks2 = 0; ks2 < 2; ++ks2) {
                int ks = st*2 + ks2;
                U4 av;
                #pragma unroll
                for (int j = 0; j < 8; ++j)
                    av.us[j] = f2bf(sTf[(ks2*32 + kq*8 + j)*68 + w*16 + rr]);
                #pragma unroll
                for (int cg = 0; cg < 4; ++cg) {
                    bf16x8 bv = *(const bf16x8*)&sBb[(cg*16 + rr)*264 + ks*32 + kq*8];
                    acc[cg] = __builtin_amdgcn_mfma_f32_16x16x32_bf16(av.bv, bv, acc[cg], 0, 0, 0);
                }
            }
            __syncthreads();
        }
        #pragma unroll
        for (int cg = 0; cg < 4; ++cg)
            #pragma unroll
            for (int e = 0; e < 4; ++e) {
                int row = row0 + w*16 + kq*4 + e;
                int col = col0 + cg*16 + rr;
                Qt[(size_t)row*256 + col] = f2bf(acc[cg][e]);
            }
    } else if (b < 160) {
        float (*tile)[33] = (float(*)[33])sPool;
        int tx = tid & 31, ty = tid >> 5;
        for (int ti = 0; ti < 4; ++ti) {
            int bi = (b - 96)*4 + ti;
            int c0 = (bi & 31) * 32, r0 = (bi >> 5) * 32;
            if (ti) __syncthreads();
            #pragma unroll
            for (int i = 0; i < 4; ++i)
                tile[ty + i*8][tx] = ffn1_w[(size_t)(r0 + ty + i*8)*1024 + c0 + tx];
            __syncthreads();
            #pragma unroll
            for (int i = 0; i < 4; ++i)
                w1t[(size_t)(c0 + ty + i*8)*256 + r0 + tx] = f2bf(tile[tx][ty + i*8]);
        }
    } else if (b < 224) {
        float (*tile)[33] = (float(*)[33])sPool;
        int tx = tid & 31, ty = tid >> 5;
        for (int ti = 0; ti < 4; ++ti) {
            int bi = (b - 160)*4 + ti;
            int c0 = (bi & 7) * 32, r0 = (bi >> 3) * 32;
            if (ti) __syncthreads();
            #pragma unroll
            for (int i = 0; i < 4; ++i)
                tile[ty + i*8][tx] = ffn2_w[(size_t)(r0 + ty + i*8)*256 + c0 + tx];
            __syncthreads();
            #pragma unroll
            for (int i = 0; i < 4; ++i)
                w2t[(size_t)(c0 + ty + i*8)*1024 + r0 + tx] = f2bf(tile[tx][ty + i*8]);
        }
    } else if (b < 228) {
        int which = b - 224;
        int o = tid;
        float a0 = 0.f, a1 = 0.f, a2 = 0.f, a3 = 0.f;
        if (which == 3) {
            const float* p = out_w + o;
            for (int r = 0; r < 768; r += 8) {
                a0 += wv0_b[r+0] * p[(size_t)(r+0)*256];
                a1 += wv0_b[r+1] * p[(size_t)(r+1)*256];
                a2 += wv0_b[r+2] * p[(size_t)(r+2)*256];
                a3 += wv0_b[r+3] * p[(size_t)(r+3)*256];
                a0 += wv0_b[r+4] * p[(size_t)(r+4)*256];
                a1 += wv0_b[r+5] * p[(size_t)(r+5)*256];
                a2 += wv0_b[r+6] * p[(size_t)(r+6)*256];
                a3 += wv0_b[r+7] * p[(size_t)(r+7)*256];
            }
            bias0[o] = out_b[o] + TAUF * ((a0+a1) + (a2+a3));
        } else {
            const float* p = out_w + (size_t)(768 + which*256)*256 + o;
            const float* wb = wein_b + which*256;
            for (int r = 0; r < 256; r += 8) {
                a0 += wb[r+0] * p[(size_t)(r+0)*256];
                a1 += wb[r+1] * p[(size_t)(r+1)*256];
                a2 += wb[r+2] * p[(size_t)(r+2)*256];
                a3 += wb[r+3] * p[(size_t)(r+3)*256];
                a0 += wb[r+4] * p[(size_t)(r+4)*256];
                a1 += wb[r+5] * p[(size_t)(r+5)*256];
                a2 += wb[r+6] * p[(size_t)(r+6)*256];
                a3 += wb[r+7] * p[(size_t)(r+7)*256];
            }
            ce[which*256 + o] = (a0+a1) + (a2+a3);
        }
    } else if (b == 228) {
        int p = tid >> 4, q = tid & 15;
        float c1 = 0.f;
        for (int e = 0; e < 120; ++e) c1 += absB1[p*120+e] * absB1[q*120+e];
        C1[tid] = c1;
        if (tid < 16) {
            float bb = 0.f;
            for (int e = 0; e < 120; ++e) bb += absB1[tid*120+e];
            r2[tid] = bb;
        }
    } else if (b < 247) {
        unsigned short (*sFrag)[8] = (unsigned short(*)[8])sPool;
        int kt = b - 229;
        #pragma unroll
        for (int it = 0; it < 2; ++it) {
            int item = it*256 + tid;
            int lane = item >> 3, j = item & 7;
            int col = lane & 15, kq = lane >> 4;
            int t = kt*32 + kq*8 + j;
            float v = 0.f;
            if (t < 560) {
                for (int e = 0; e < 120; ++e) v += absB1[col*120+e] * B2g[e*560+t];
            } else {
                int p = t - 560;
                for (int e = 0; e < 120; ++e) v += absB1[col*120+e] * B1g[p*120+e];
            }
            sFrag[lane][j] = f2bf(v);
        }
        __syncthreads();
        if (tid < 64) {
            U4 o;
            #pragma unroll
            for (int j = 0; j < 8; ++j) o.us[j] = sFrag[tid][j];
            ufrag[kt*64 + tid] = o.u4;
        }
    } else if (b < 251) {
        if (tid < 64) {
            int lane = tid, col = lane & 15, kq = lane >> 4;
            int kt = b - 247;
            U4 o;
            #pragma unroll
            for (int j = 0; j < 8; ++j) {
                int e = kt*32 + kq*8 + j;
                o.us[j] = f2bf((e < 120) ? B1g[col*120 + e] : 0.f);
            }
            b1frag[kt*64 + lane] = o.u4;
        }
    } else {
        unsigned short (*sFrag)[8] = (unsigned short(*)[8])sPool;
        int kt = b - 251;
        #pragma unroll
        for (int it = 0; it < 2; ++it) {
            int item = it*256 + tid;
            int lane = item >> 3, j = item & 7;
            int col = lane & 15, kq = lane >> 4;
            int t = kt*32 + kq*8 + j;
            float g;
            if (t < 560) {
                float u = 0.f, sgv = 0.f;
                for (int e = 0; e < 120; ++e) {
                    float bv = B2g[e*560+t];
                    u += absB1[col*120+e] * bv;
                    sgv += bv;
                }
                g = sgv * u;
            } else {
                int p = t - 560;
                float c0 = 0.f, r1v = 0.f;
                for (int e = 0; e < 120; ++e) {
                    float bv = B1g[p*120+e];
                    c0 += absB1[col*120+e] * bv;
                    r1v += bv;
                }
                g = c0 * r1v;
            }
            sFrag[lane][j] = f2bf(g);
        }
        __syncthreads();
        if (tid < 64) {
            U4 o;
            #pragma unroll
            for (int j = 0; j < 8; ++j) o.us[j] = sFrag[tid][j];
            gfrag[kt*64 + tid] = o.u4;
        }
    }
}

// ============== k_mega: R16 structure + barrier-exit load hoists ==============
__launch_bounds__(1024, 4)
__global__ void k_mega(const float* __restrict__ x, const float* __restrict__ mask,
                       const int* __restrict__ e_i, const int* __restrict__ e_j,
                       const int* __restrict__ t_ij, const int* __restrict__ t_jk,
                       const int* __restrict__ t_ik,
                       const float* __restrict__ geom_w, const float* __restrict__ geom_b,
                       const float* __restrict__ log_sc,
                       const float* __restrict__ n1_g, const float* __restrict__ n1_b,
                       const float* __restrict__ n2g, const float* __restrict__ n2b,
                       const float* __restrict__ C1, const float* __restrict__ r2,
                       const uint4* __restrict__ ufrag, const uint4* __restrict__ b1frag,
                       const uint4* __restrict__ gfrag,
                       const unsigned short* __restrict__ Qt,
                       const float* __restrict__ bias0, const float* __restrict__ ce,
                       const unsigned short* __restrict__ w1t, const float* __restrict__ f1b,
                       const unsigned short* __restrict__ w2t, const float* __restrict__ f2b,
                       float* __restrict__ outp)
{
    __shared__ float sFbuf[16][264];           // xn (A..B), then x2 (F..I)
    __shared__ unsigned short sNB[16*256];     // bf16 xn chunks (A..F), then x2n (G,H)
    __shared__ unsigned short sH[16*1024];     // h, frag layout
    __shared__ float sP[16][17];
    __shared__ float sW1e[3][128];
    __shared__ float sW2e[3][576];
    __shared__ float sMask[16];
    __shared__ float sO[6*256];
    __shared__ float sRsA[48];
    __shared__ int sCnt[4];
    __shared__ int sFlagO;

    const int bb = blockIdx.x, tid = threadIdx.x;
    const int w = tid >> 6, lane = tid & 63;
    const int rr = lane & 15, kq = lane >> 4;

    // ---- A. LayerNorm 1 (all waves) + flag init ----
    {
        if (tid < 4) sCnt[tid] = 0;
        if (tid == 4) sFlagO = 0;
        const int r = w, q = lane;
        const float* row = x + ((size_t)bb*16 + r)*256 + q*4;
        float4 va = *(const float4*)row;
        float v[4] = {va.x, va.y, va.z, va.w};
        float sum = v[0]+v[1]+v[2]+v[3];
        float ss  = v[0]*v[0]+v[1]*v[1]+v[2]*v[2]+v[3]*v[3];
        #pragma unroll
        for (int o = 32; o; o >>= 1) { sum += __shfl_xor(sum, o); ss += __shfl_xor(ss, o); }
        float mean = sum * (1.f/256.f);
        float rstd = rsqrtf(ss*(1.f/256.f) - mean*mean + LNEPS);
        ushort4 pk;
        float xv0 = (v[0]-mean)*rstd*n1_g[q*4+0] + n1_b[q*4+0];
        float xv1 = (v[1]-mean)*rstd*n1_g[q*4+1] + n1_b[q*4+1];
        float xv2 = (v[2]-mean)*rstd*n1_g[q*4+2] + n1_b[q*4+2];
        float xv3 = (v[3]-mean)*rstd*n1_g[q*4+3] + n1_b[q*4+3];
        sFbuf[r][q*4+0] = xv0; sFbuf[r][q*4+1] = xv1;
        sFbuf[r][q*4+2] = xv2; sFbuf[r][q*4+3] = xv3;
        pk.x = f2bf(xv0); pk.y = f2bf(xv1); pk.z = f2bf(xv2); pk.w = f2bf(xv3);
        int kg = q >> 1;
        int swz = (kg & 24) | ((kg & 7) ^ (r & 7));
        *(ushort4*)&sNB[r*256 + swz*8 + (q & 1)*4] = pk;
        if (tid < 16) sMask[tid] = mask[bb*16 + tid];
    }
    __syncthreads();                                     // barrier #1

    auto team_bar = [&](int idx) {
        if ((tid & 63) == 0)
            __hip_atomic_fetch_add(&sCnt[idx], 1, __ATOMIC_ACQ_REL, __HIP_MEMORY_SCOPE_WORKGROUP);
        while (__hip_atomic_load(&sCnt[idx], __ATOMIC_ACQUIRE, __HIP_MEMORY_SCOPE_WORKGROUP) < 5)
            __builtin_amdgcn_s_sleep(1);
    };

    if (w < 5) {
        // ================== GEO TEAM (waves 0-4) ==================
        if (tid < 256) {
            int r = tid >> 4, g = tid & 15;
            float a0 = 0.f, a1 = 0.f, a2 = 0.f, a3 = 0.f;
            for (int c = 0; c < 256; c += 4) {
                float4 xv = *(const float4*)&sFbuf[r][c];
                a0 += xv.x * geom_w[(c+0)*16 + g];
                a1 += xv.y * geom_w[(c+1)*16 + g];
                a2 += xv.z * geom_w[(c+2)*16 + g];
                a3 += xv.w * geom_w[(c+3)*16 + g];
            }
            sP[r][g] = (a0+a1) + (a2+a3) + geom_b[g];
        }
        team_bar(0);
        if (tid < 120) {
            int e = tid, i0 = e_i[e], j0 = e_j[e];
            float d2 = 0.f;
            #pragma unroll
            for (int m = 0; m < 16; ++m) { float dd = sP[i0][m] - sP[j0][m]; d2 += dd*dd; }
            float mm = sMask[i0]*sMask[j0];
            d2 *= mm*mm;
            #pragma unroll
            for (int s = 0; s < 3; ++s) {
                float sc = __expf(log_sc[s]);
                sW1e[s][e] = __expf(-d2/(2.f*sc*sc + 1e-8f)) * mm;
            }
        }
        if (tid < 24) sW1e[tid >> 3][120 + (tid & 7)] = 0.f;
        team_bar(1);
        for (int t = tid; t < 560; t += 320) {
            int a = t_ij[t], b2 = t_jk[t], c2 = t_ik[t];
            #pragma unroll
            for (int s = 0; s < 3; ++s) sW2e[s][t] = sW1e[s][a]*sW1e[s][b2]*sW1e[s][c2];
        }
        if (tid < 48) sW2e[tid >> 4][560 + (tid & 15)] = sMask[tid & 15];
        team_bar(2);
        if (w < 3) {
            int s = w;
            f32x4 acc = {0.f, 0.f, 0.f, 0.f};
            __builtin_amdgcn_s_setprio(1);
            #pragma unroll 3
            for (int kt = 0; kt < 18; ++kt) {
                U4 ub; ub.u4 = ufrag[kt*64 + lane];
                const float4* w4 = (const float4*)&sW2e[s][kt*32 + kq*8];
                float4 wa = w4[0], wb = w4[1];
                U4 av;
                av.us[0] = f2bf(wa.x * bf2f(ub.us[0]));
                av.us[1] = f2bf(wa.y * bf2f(ub.us[1]));
                av.us[2] = f2bf(wa.z * bf2f(ub.us[2]));
                av.us[3] = f2bf(wa.w * bf2f(ub.us[3]));
                av.us[4] = f2bf(wb.x * bf2f(ub.us[4]));
                av.us[5] = f2bf(wb.y * bf2f(ub.us[5]));
                av.us[6] = f2bf(wb.z * bf2f(ub.us[6]));
                av.us[7] = f2bf(wb.w * bf2f(ub.us[7]));
                acc = __builtin_amdgcn_mfma_f32_16x16x32_bf16(av.bv, ub.bv, acc, 0, 0, 0);
            }
            __builtin_amdgcn_s_setprio(0);
            #pragma unroll
            for (int e = 0; e < 4; ++e) {
                int row = kq*4 + e;
                sO[(3+s)*256 + row*16 + rr] = acc[e] + TAUF*C1[row*16 + rr];
            }
        } else if (w == 3) {
            f32x4 acc3[3];
            acc3[0] = 0.f; acc3[1] = 0.f; acc3[2] = 0.f;
            __builtin_amdgcn_s_setprio(1);
            #pragma unroll
            for (int kt = 0; kt < 4; ++kt) {
                U4 ub; ub.u4 = b1frag[kt*64 + lane];
                float uf[8];
                #pragma unroll
                for (int j = 0; j < 8; ++j) uf[j] = bf2f(ub.us[j]);
                #pragma unroll
                for (int s = 0; s < 3; ++s) {
                    const float4* w4 = (const float4*)&sW1e[s][kt*32 + kq*8];
                    float4 wa = w4[0], wb = w4[1];
                    U4 av;
                    av.us[0] = f2bf(wa.x * uf[0]);
                    av.us[1] = f2bf(wa.y * uf[1]);
                    av.us[2] = f2bf(wa.z * uf[2]);
                    av.us[3] = f2bf(wa.w * uf[3]);
                    av.us[4] = f2bf(wb.x * uf[4]);
                    av.us[5] = f2bf(wb.y * uf[5]);
                    av.us[6] = f2bf(wb.z * uf[6]);
                    av.us[7] = f2bf(wb.w * uf[7]);
                    acc3[s] = __builtin_amdgcn_mfma_f32_16x16x32_bf16(av.bv, ub.bv, acc3[s], 0, 0, 0);
                }
            }
            __builtin_amdgcn_s_setprio(0);
            #pragma unroll
            for (int s = 0; s < 3; ++s)
                #pragma unroll
                for (int e = 0; e < 4; ++e) {
                    int row = kq*4 + e;
                    sO[s*256 + row*16 + rr] = acc3[s][e] + ((row == rr) ? TAUF : 0.f);
                }
        } else {
            f32x4 acc = {0.f, 0.f, 0.f, 0.f};
            int srow = (rr < 3) ? rr : 0;
            __builtin_amdgcn_s_setprio(1);
            #pragma unroll 3
            for (int kt = 0; kt < 18; ++kt) {
                U4 gb; gb.u4 = gfrag[kt*64 + lane];
                const float4* w4 = (const float4*)&sW2e[srow][kt*32 + kq*8];
                float4 wa = w4[0], wb = w4[1];
                U4 av;
                av.us[0] = f2bf(wa.x); av.us[1] = f2bf(wa.y);
                av.us[2] = f2bf(wa.z); av.us[3] = f2bf(wa.w);
                av.us[4] = f2bf(wb.x); av.us[5] = f2bf(wb.y);
                av.us[6] = f2bf(wb.z); av.us[7] = f2bf(wb.w);
                acc = __builtin_amdgcn_mfma_f32_16x16x32_bf16(av.bv, gb.bv, acc, 0, 0, 0);
            }
            __builtin_amdgcn_s_setprio(0);
            if (kq == 0) {
                #pragma unroll
                for (int e = 0; e < 3; ++e)
                    sRsA[e*16 + rr] = acc[e] + TAUF * r2[rr];
            }
        }
        team_bar(3);
        if (tid == 0)
            __hip_atomic_store(&sFlagO, 1, __ATOMIC_RELEASE, __HIP_MEMORY_SCOPE_WORKGROUP);

        // F (geo team's own col-tile 11+w)
        {
            const int col = (11 + w)*16 + rr;
            float accP[16];
            #pragma unroll
            for (int k = 0; k < 16; ++k) accP[k] = 0.f;
            for (int blk = 0; blk < 6; ++blk) {
                f32x4 ya = {0.f, 0.f, 0.f, 0.f};
                #pragma unroll
                for (int half = 0; half < 2; ++half) {
                    U4 qf[4];
                    #pragma unroll
                    for (int kt = 0; kt < 4; ++kt)
                        qf[kt].u4 = *(const uint4*)(Qt + ((size_t)(blk*256 + (11+w)*16 + rr))*256 + (half*4 + kt)*32 + kq*8);
                    #pragma unroll
                    for (int kt = 0; kt < 4; ++kt) {
                        int kg = (half*4 + kt)*4 + kq;
                        int swz = (kg & 24) | ((kg & 7) ^ (rr & 7));
                        bf16x8 af = *(const bf16x8*)&sNB[rr*256 + swz*8];
                        ya = __builtin_amdgcn_mfma_f32_16x16x32_bf16(af, qf[kt].bv, ya, 0, 0, 0);
                    }
                }
                #pragma unroll
                for (int k = 0; k < 16; ++k) {
                    float4 ov = *(const float4*)&sO[blk*256 + k*16 + kq*4];
                    accP[k] += ov.x*ya[0] + ov.y*ya[1] + ov.z*ya[2] + ov.w*ya[3];
                }
            }
            #pragma unroll
            for (int k = 0; k < 16; ++k) {
                accP[k] += __shfl_xor(accP[k], 16);
                accP[k] += __shfl_xor(accP[k], 32);
            }
            float b0v = bias0[col], c0v = ce[col], c1v = ce[256+col], c2v = ce[512+col];
            #pragma unroll
            for (int e = 0; e < 4; ++e) {
                int k = kq*4 + e;
                float v = accP[k] + b0v
                        + sRsA[     k] * c0v
                        + sRsA[16 + k] * c1v
                        + sRsA[32 + k] * c2v
                        + x[((size_t)bb*16 + k)*256 + col];
                sFbuf[k][col] = v;
            }
        }
    } else {
        // ================== Y TEAM (waves 5-15): tile w-5, overlaps with geometry ==================
        const int ty = w - 5;
        const int col = ty*16 + rr;
        f32x4 ya[6];
        #pragma unroll
        for (int blk = 0; blk < 6; ++blk) {
            ya[blk] = 0.f;
            #pragma unroll
            for (int half = 0; half < 2; ++half) {
                U4 qf[4];
                #pragma unroll
                for (int kt = 0; kt < 4; ++kt)
                    qf[kt].u4 = *(const uint4*)(Qt + ((size_t)(blk*256 + ty*16 + rr))*256 + (half*4 + kt)*32 + kq*8);
                #pragma unroll
                for (int kt = 0; kt < 4; ++kt) {
                    int kg = (half*4 + kt)*4 + kq;
                    int swz = (kg & 24) | ((kg & 7) ^ (rr & 7));
                    bf16x8 af = *(const bf16x8*)&sNB[rr*256 + swz*8];
                    ya[blk] = __builtin_amdgcn_mfma_f32_16x16x32_bf16(af, qf[kt].bv, ya[blk], 0, 0, 0);
                }
            }
        }
        // residual prefetch: loads complete while spinning on the flag
        float xr[4];
        #pragma unroll
        for (int e = 0; e < 4; ++e)
            xr[e] = x[((size_t)bb*16 + kq*4 + e)*256 + col];
        while (__hip_atomic_load(&sFlagO, __ATOMIC_ACQUIRE, __HIP_MEMORY_SCOPE_WORKGROUP) == 0)
            __builtin_amdgcn_s_sleep(1);
        float accP[16];
        #pragma unroll
        for (int k = 0; k < 16; ++k) accP[k] = 0.f;
        #pragma unroll
        for (int blk = 0; blk < 6; ++blk)
            #pragma unroll
            for (int k = 0; k < 16; ++k) {
                float4 ov = *(const float4*)&sO[blk*256 + k*16 + kq*4];
                accP[k] += ov.x*ya[blk][0] + ov.y*ya[blk][1] + ov.z*ya[blk][2] + ov.w*ya[blk][3];
            }
        #pragma unroll
        for (int k = 0; k < 16; ++k) {
            accP[k] += __shfl_xor(accP[k], 16);
            accP[k] += __shfl_xor(accP[k], 32);
        }
        float b0v = bias0[col], c0v = ce[col], c1v = ce[256+col], c2v = ce[512+col];
        #pragma unroll
        for (int e = 0; e < 4; ++e) {
            int k = kq*4 + e;
            float v = accP[k] + b0v
                    + sRsA[     k] * c0v
                    + sRsA[16 + k] * c1v
                    + sRsA[32 + k] * c2v
                    + xr[e];
            sFbuf[k][col] = v;
        }
    }
    __syncthreads();                                     // barrier #2

    // ---- G. LN2 -> sNB; H's first wb prefetch hoisted (independent of sNB) ----
    U4 wb[8];
    #pragma unroll
    for (int kt = 0; kt < 8; ++kt)
        wb[kt].u4 = *(const uint4*)(w1t + (size_t)((w*4+0)*16 + rr)*256 + kt*32 + kq*8);
    {
        const int r = w, q = lane;
        float v[4];
        v[0] = sFbuf[r][q*4+0]; v[1] = sFbuf[r][q*4+1];
        v[2] = sFbuf[r][q*4+2]; v[3] = sFbuf[r][q*4+3];
        float sum = v[0]+v[1]+v[2]+v[3];
        float ss  = v[0]*v[0]+v[1]*v[1]+v[2]*v[2]+v[3]*v[3];
        #pragma unroll
        for (int o = 32; o; o >>= 1) { sum += __shfl_xor(sum, o); ss += __shfl_xor(ss, o); }
        float mean = sum * (1.f/256.f);
        float rstd = rsqrtf(ss*(1.f/256.f) - mean*mean + LNEPS);
        ushort4 pk;
        pk.x = f2bf((v[0]-mean)*rstd*n2g[q*4+0] + n2b[q*4+0]);
        pk.y = f2bf((v[1]-mean)*rstd*n2g[q*4+1] + n2b[q*4+1]);
        pk.z = f2bf((v[2]-mean)*rstd*n2g[q*4+2] + n2b[q*4+2]);
        pk.w = f2bf((v[3]-mean)*rstd*n2g[q*4+3] + n2b[q*4+3]);
        int kg = q >> 1;
        int swz = (kg & 24) | ((kg & 7) ^ (r & 7));
        *(ushort4*)&sNB[r*256 + swz*8 + (q & 1)*4] = pk;
    }
    __syncthreads();                                     // barrier #3

    // ---- H. FFN1: wave w -> 4 n-tiles; h -> sH (cheap gelu) ----
    {
        #pragma unroll
        for (int j = 0; j < 4; ++j) {
            int nt = w*4 + j;
            f32x4 acc = {0.f, 0.f, 0.f, 0.f};
            __builtin_amdgcn_s_setprio(1);
            #pragma unroll
            for (int kt = 0; kt < 8; ++kt) {
                int kg = kt*4 + kq;
                int swz = (kg & 24) | ((kg & 7) ^ (rr & 7));
                bf16x8 af = *(const bf16x8*)&sNB[rr*256 + swz*8];
                acc = __builtin_amdgcn_mfma_f32_16x16x32_bf16(af, wb[kt].bv, acc, 0, 0, 0);
            }
            __builtin_amdgcn_s_setprio(0);
            if (j < 3) {
                #pragma unroll
                for (int kt = 0; kt < 8; ++kt)
                    wb[kt].u4 = *(const uint4*)(w1t + (size_t)((nt+1)*16 + rr)*256 + kt*32 + kq*8);
            }
            int n = nt*16 + rr;
            float bias = f1b[n];
            int hkg = n >> 3, hlo = n & 7;
            #pragma unroll
            for (int e = 0; e < 4; ++e) {
                int m = kq*4 + e;
                float v = acc[e] + bias;
                v = v / (1.f + __expf(-1.702f * v));          // gelu ~ v*sigmoid(1.702v)
                int hswz = (hkg & 120) | ((hkg & 7) ^ (m & 7));
                sH[m*1024 + hswz*8 + hlo] = f2bf(v);
            }
        }
    }
    // I's first qb prefetch hoisted above barrier #4 (w2t independent of sH)
    U4 qb[8];
    #pragma unroll
    for (int kt = 0; kt < 8; ++kt)
        qb[kt].u4 = *(const uint4*)(w2t + (size_t)(w*16 + rr)*1024 + kt*32 + kq*8);
    __syncthreads();                                     // barrier #4

    // ---- I. FFN2: wave w -> 1 n-tile; out = x2 + h @ w2t^T + b2 ----
    {
        f32x4 acc = {0.f, 0.f, 0.f, 0.f};
        #pragma unroll
        for (int grp = 0; grp < 4; ++grp) {
            __builtin_amdgcn_s_setprio(1);
            #pragma unroll
            for (int kt = 0; kt < 8; ++kt) {
                int hkg = (grp*8 + kt)*4 + kq;
                int hswz = (hkg & 120) | ((hkg & 7) ^ (rr & 7));
                bf16x8 af = *(const bf16x8*)&sH[rr*1024 + hswz*8];
                acc = __builtin_amdgcn_mfma_f32_16x16x32_bf16(af, qb[kt].bv, acc, 0, 0, 0);
            }
            __builtin_amdgcn_s_setprio(0);
            if (grp < 3) {
                #pragma unroll
                for (int kt = 0; kt < 8; ++kt)
                    qb[kt].u4 = *(const uint4*)(w2t + (size_t)(w*16 + rr)*1024 + ((grp+1)*8 + kt)*32 + kq*8);
            }
        }
        int col = w*16 + rr;
        float bias = f2b[col];
        #pragma unroll
        for (int e = 0; e < 4; ++e) {
            int row = kq*4 + e;
            outp[((size_t)bb*16 + row)*256 + col] = acc[e] + bias + sFbuf[row][col];
        }
    }
}

extern "C" void kernel_launch(void* const* d_in, const int* in_sizes, int n_in,
                              void* d_out, int out_size, void* d_ws, size_t ws_size,
                              hipStream_t stream)
{
    (void)in_sizes; (void)n_in; (void)out_size;
    const float* x      = (const float*)d_in[0];
    const float* mask   = (const float*)d_in[1];
    const float* B1g    = (const float*)d_in[2];
    const float* B2g    = (const float*)d_in[3];
    const float* absB1  = (const float*)d_in[4];
    const int*   e_i    = (const int*)d_in[5];
    const int*   e_j    = (const int*)d_in[6];
    const int*   t_ij   = (const int*)d_in[7];
    const int*   t_jk   = (const int*)d_in[8];
    const int*   t_ik   = (const int*)d_in[9];
    const float* geom_w = (const float*)d_in[10];
    const float* geom_b = (const float*)d_in[11];
    const float* log_sc = (const float*)d_in[12];
    const float* wv0_w  = (const float*)d_in[13];
    const float* wv0_b  = (const float*)d_in[14];
    const float* wein_w = (const float*)d_in[15];
    const float* wein_b = (const float*)d_in[16];
    const float* out_w  = (const float*)d_in[17];
    const float* out_b  = (const float*)d_in[18];
    const float* n1_g   = (const float*)d_in[19];
    const float* n1_b   = (const float*)d_in[20];
    const float* n2_g   = (const float*)d_in[21];
    const float* n2_b   = (const float*)d_in[22];
    const float* ffn1_w = (const float*)d_in[23];
    const float* ffn1_b = (const float*)d_in[24];
    const float* ffn2_w = (const float*)d_in[25];
    const float* ffn2_b = (const float*)d_in[26];

    float* out = (float*)d_out;
    float* ws  = (float*)d_ws;
    if (ws_size < (size_t)WS_FLOATS * sizeof(float)) return;

    float* ce    = ws + CE_OFF;
    float* bias0 = ws + B0_OFF;
    float* C1    = ws + C1_OFF;
    float* r2    = ws + R2_OFF;
    uint4* ufrag  = (uint4*)(ws + UF_OFF);
    uint4* b1frag = (uint4*)(ws + B1F_OFF);
    uint4* gfrag  = (uint4*)(ws + GF_OFF);
    unsigned short* Qt  = (unsigned short*)(ws + QT_OFF);
    unsigned short* w1t = (unsigned short*)(ws + W1T_OFF);
    unsigned short* w2t = (unsigned short*)(ws + W2T_OFF);

    prep_k<<<269, 256, 0, stream>>>(wv0_w, wein_w, out_w, ffn1_w, ffn2_w,
                                    wv0_b, wein_b, out_b, B1g, absB1, B2g,
                                    Qt, w1t, w2t,
                                    ce, bias0, C1, r2,
                                    ufrag, b1frag, gfrag);
    k_mega<<<256, 1024, 0, stream>>>(x, mask, e_i, e_j, t_ij, t_jk, t_ik,
                                     geom_w, geom_b, log_sc, n1_g, n1_b, n2_g, n2_b,
                                     C1, r2, ufrag, b1frag, gfrag,
                                     Qt, bias0, ce,
                                     w1t, ffn1_b, w2t, ffn2_b, out);
}